// Round 1
// baseline (361.568 us; speedup 1.0000x reference)
//
#include <hip/hip_runtime.h>
#include <math.h>

#define NNODES 50000
#define NEDGES 800000

// ---------------- CSR build ----------------

__global__ void k_hist(const int* __restrict__ dst, int* __restrict__ deg, int E) {
    int e = blockIdx.x * blockDim.x + threadIdx.x;
    if (e < E) atomicAdd(&deg[dst[e]], 1);
}

// per-block exclusive scan over 1024 elements; block totals to partial[]
__global__ void k_scan_block(const int* __restrict__ deg, int* __restrict__ offs,
                             int* __restrict__ partial, int N) {
    __shared__ int tmp[1024];
    int t = threadIdx.x;
    int i = blockIdx.x * 1024 + t;
    int v = (i < N) ? deg[i] : 0;
    tmp[t] = v;
    __syncthreads();
    for (int off = 1; off < 1024; off <<= 1) {
        int u = (t >= off) ? tmp[t - off] : 0;
        __syncthreads();
        tmp[t] += u;
        __syncthreads();
    }
    if (i < N) offs[i] = tmp[t] - v;            // exclusive within block
    if (t == 1023) partial[blockIdx.x] = tmp[t]; // block total
}

// single-wave exclusive scan of block partials (nb <= 64); writes offs[N]=total
__global__ void k_scan_partial(int* __restrict__ partial, int* __restrict__ offs,
                               int nb, int N) {
    int l = threadIdx.x;  // 64 threads = 1 wave
    int v = (l < nb) ? partial[l] : 0;
    int incl = v;
    #pragma unroll
    for (int off = 1; off < 64; off <<= 1) {
        int u = __shfl_up(incl, off, 64);
        if (l >= off) incl += u;
    }
    if (l < nb) partial[l] = incl - v;  // exclusive
    if (l == 63) offs[N] = incl;        // grand total (== E)
}

__global__ void k_scan_add(int* __restrict__ offs, const int* __restrict__ partial, int N) {
    int i = blockIdx.x * 1024 + threadIdx.x;
    if (i < N) offs[i] += partial[blockIdx.x];
}

__global__ void k_scatter(const int* __restrict__ src, const int* __restrict__ dst,
                          const int* __restrict__ offs, int* __restrict__ cursor,
                          int* __restrict__ esrc, int E) {
    int e = blockIdx.x * blockDim.x + threadIdx.x;
    if (e < E) {
        int d = dst[e];
        int pos = offs[d] + atomicAdd(&cursor[d], 1);
        esrc[pos] = src[e];
    }
}

// ---------------- GEMM + attention-logit epilogue ----------------
// H[n][j] = sum_k X[n][k] * W[k][j];  AS[n] = H[n]·a_src; AD[n] = H[n]·a_dst
template<int K>
__global__ __launch_bounds__(256) void k_gemm_att(
    const float* __restrict__ X, const float* __restrict__ W,
    const float* __restrict__ a_src, const float* __restrict__ a_dst,
    float* __restrict__ H, float* __restrict__ AS, float* __restrict__ AD, int N)
{
    __shared__ float Wl[K * 64];
    int t = threadIdx.x;  // 256 threads = 4 waves, one node per wave
    for (int i = t; i < K * 64; i += 256) Wl[i] = W[i];
    int lane = t & 63;
    float asj = a_src[lane], adj = a_dst[lane];
    __syncthreads();
    int n = blockIdx.x * 4 + (t >> 6);
    if (n >= N) return;
    const float4* xr = (const float4*)(X + (size_t)n * K);
    float acc = 0.f;
    #pragma unroll
    for (int k4 = 0; k4 < K / 4; ++k4) {
        float4 xv = xr[k4];  // wave-uniform broadcast load
        acc += xv.x * Wl[(k4 * 4 + 0) * 64 + lane];
        acc += xv.y * Wl[(k4 * 4 + 1) * 64 + lane];
        acc += xv.z * Wl[(k4 * 4 + 2) * 64 + lane];
        acc += xv.w * Wl[(k4 * 4 + 3) * 64 + lane];
    }
    float s1 = acc * asj, s2 = acc * adj;
    #pragma unroll
    for (int o = 32; o > 0; o >>= 1) {
        s1 += __shfl_xor(s1, o, 64);
        s2 += __shfl_xor(s2, o, 64);
    }
    H[(size_t)n * 64 + lane] = acc;
    if (lane == 0) { AS[n] = s1; AD[n] = s2; }
}

// ---------------- per-dst online-softmax aggregation ----------------
// one wave per destination node; lane = feature index
template<int RELU, int NORM>
__global__ __launch_bounds__(256) void k_agg(
    const int* __restrict__ esrc, const int* __restrict__ offs,
    const float* __restrict__ H, const float* __restrict__ AS,
    const float* __restrict__ AD, const float* __restrict__ bias,
    float* __restrict__ out, int N)
{
    int gid = blockIdx.x * blockDim.x + threadIdx.x;
    int w = gid >> 6;
    int lane = gid & 63;
    if (w >= N) return;
    int beg = offs[w], end = offs[w + 1];
    float add = AD[w];
    float m = -3.0e38f, z = 0.f, acc = 0.f;
    for (int i = beg; i < end; ++i) {
        int s = esrc[i];                     // wave-uniform broadcast
        float logit = AS[s] + add;
        logit = (logit > 0.f) ? logit : logit * 0.2f;  // leaky_relu 0.2
        float hv = H[(size_t)s * 64 + lane]; // coalesced 256B gather
        float mn = fmaxf(m, logit);
        float sc = __expf(m - mn);
        float wg = __expf(logit - mn);
        z   = z * sc + wg;
        acc = acc * sc + wg * hv;
        m = mn;
    }
    float val = (end > beg) ? (acc / z + bias[lane]) : bias[lane];
    if (RELU) val = fmaxf(val, 0.f);
    if (NORM) {
        float ss = val * val;
        #pragma unroll
        for (int o = 32; o > 0; o >>= 1) ss += __shfl_xor(ss, o, 64);
        float nrm = sqrtf(ss);
        val = val / fmaxf(nrm, 1e-12f);
    }
    out[(size_t)w * 64 + lane] = val;
}

// ---------------- launch ----------------

extern "C" void kernel_launch(void* const* d_in, const int* in_sizes, int n_in,
                              void* d_out, int out_size, void* d_ws, size_t ws_size,
                              hipStream_t stream) {
    const float* x   = (const float*)d_in[0];
    const int*   ei  = (const int*)d_in[1];
    const float* W1  = (const float*)d_in[2];
    const float* as1 = (const float*)d_in[3];
    const float* ad1 = (const float*)d_in[4];
    const float* b1  = (const float*)d_in[5];
    const float* W2  = (const float*)d_in[6];
    const float* as2 = (const float*)d_in[7];
    const float* ad2 = (const float*)d_in[8];
    const float* b2  = (const float*)d_in[9];
    const int* src = ei;
    const int* dst = ei + NEDGES;

    char* ws = (char*)d_ws;
    size_t off = 0;
    auto alloc = [&](size_t bytes) -> void* {
        void* p = ws + off;
        off = (off + bytes + 255) & ~(size_t)255;
        return p;
    };
    float* H    = (float*)alloc((size_t)NNODES * 64 * 4);
    float* OUT1 = (float*)alloc((size_t)NNODES * 64 * 4);
    float* AS   = (float*)alloc((size_t)NNODES * 4);
    float* AD   = (float*)alloc((size_t)NNODES * 4);
    int* offs   = (int*)alloc((size_t)(NNODES + 1) * 4);
    int* deg    = (int*)alloc((size_t)NNODES * 4);
    int* cursor = (int*)alloc((size_t)NNODES * 4);
    int* esrc   = (int*)alloc((size_t)NEDGES * 4);
    int* partial= (int*)alloc(64 * 4);

    hipMemsetAsync(deg, 0, (size_t)NNODES * 4, stream);
    hipMemsetAsync(cursor, 0, (size_t)NNODES * 4, stream);

    // CSR build (reused by both layers; dst is identical)
    k_hist<<<(NEDGES + 255) / 256, 256, 0, stream>>>(dst, deg, NEDGES);
    int nb = (NNODES + 1023) / 1024;  // 49
    k_scan_block<<<nb, 1024, 0, stream>>>(deg, offs, partial, NNODES);
    k_scan_partial<<<1, 64, 0, stream>>>(partial, offs, nb, NNODES);
    k_scan_add<<<nb, 1024, 0, stream>>>(offs, partial, NNODES);
    k_scatter<<<(NEDGES + 255) / 256, 256, 0, stream>>>(src, dst, offs, cursor, esrc, NEDGES);

    // Layer 1: h1 = x@W1 (+logits) ; agg -> relu(agg + b1)
    k_gemm_att<128><<<(NNODES + 3) / 4, 256, 0, stream>>>(x, W1, as1, ad1, H, AS, AD, NNODES);
    k_agg<1, 0><<<((NNODES * 64) + 255) / 256, 256, 0, stream>>>(esrc, offs, H, AS, AD, b1, OUT1, NNODES);

    // Layer 2: h2 = out1@W2 (+logits) ; agg -> (agg + b2) then L2-normalize
    k_gemm_att<64><<<(NNODES + 3) / 4, 256, 0, stream>>>(OUT1, W2, as2, ad2, H, AS, AD, NNODES);
    k_agg<0, 1><<<((NNODES * 64) + 255) / 256, 256, 0, stream>>>(esrc, offs, H, AS, AD, b2, (float*)d_out, NNODES);
}

// Round 2
// 335.155 us; speedup vs baseline: 1.0788x; 1.0788x over previous
//
#include <hip/hip_runtime.h>
#include <math.h>

#define NNODES 50000
#define NEDGES 800000

// ---------------- CSR build ----------------

__global__ void k_hist(const int* __restrict__ dst, int* __restrict__ deg, int E) {
    int e = blockIdx.x * blockDim.x + threadIdx.x;
    if (e < E) atomicAdd(&deg[dst[e]], 1);
}

__global__ void k_scan_block(const int* __restrict__ deg, int* __restrict__ offs,
                             int* __restrict__ partial, int N) {
    __shared__ int tmp[1024];
    int t = threadIdx.x;
    int i = blockIdx.x * 1024 + t;
    int v = (i < N) ? deg[i] : 0;
    tmp[t] = v;
    __syncthreads();
    for (int off = 1; off < 1024; off <<= 1) {
        int u = (t >= off) ? tmp[t - off] : 0;
        __syncthreads();
        tmp[t] += u;
        __syncthreads();
    }
    if (i < N) offs[i] = tmp[t] - v;
    if (t == 1023) partial[blockIdx.x] = tmp[t];
}

__global__ void k_scan_partial(int* __restrict__ partial, int* __restrict__ offs,
                               int nb, int N) {
    int l = threadIdx.x;
    int v = (l < nb) ? partial[l] : 0;
    int incl = v;
    #pragma unroll
    for (int off = 1; off < 64; off <<= 1) {
        int u = __shfl_up(incl, off, 64);
        if (l >= off) incl += u;
    }
    if (l < nb) partial[l] = incl - v;
    if (l == 63) offs[N] = incl;
}

__global__ void k_scan_add(int* __restrict__ offs, const int* __restrict__ partial, int N) {
    int i = blockIdx.x * 1024 + threadIdx.x;
    if (i < N) offs[i] += partial[blockIdx.x];
}

__global__ void k_scatter(const int* __restrict__ src, const int* __restrict__ dst,
                          const int* __restrict__ offs, int* __restrict__ cursor,
                          int* __restrict__ esrc, int E) {
    int e = blockIdx.x * blockDim.x + threadIdx.x;
    if (e < E) {
        int d = dst[e];
        int pos = offs[d] + atomicAdd(&cursor[d], 1);
        esrc[pos] = src[e];
    }
}

// ---------------- GEMM + attention-logit epilogue ----------------
// 16 nodes per block, 4 per wave (4 independent FMA chains, W staged once/block)
template<int K>
__global__ __launch_bounds__(256) void k_gemm_att(
    const float* __restrict__ X, const float* __restrict__ W,
    const float* __restrict__ a_src, const float* __restrict__ a_dst,
    float* __restrict__ H, float* __restrict__ AS, float* __restrict__ AD, int N)
{
    __shared__ float Wl[K * 64];
    int t = threadIdx.x;
    const float4* W4 = (const float4*)W;
    float4* Wl4 = (float4*)Wl;
    for (int i = t; i < K * 16; i += 256) Wl4[i] = W4[i];
    int lane = t & 63, wid = t >> 6;
    float asj = a_src[lane], adj = a_dst[lane];
    __syncthreads();
    int n0 = (blockIdx.x * 4 + wid) * 4;
    if (n0 >= N) return;
    constexpr int KR = K / 4;
    const float4* x0 = (const float4*)(X + (size_t)n0 * K);
    float acc0 = 0.f, acc1 = 0.f, acc2 = 0.f, acc3 = 0.f;
    #pragma unroll
    for (int k4 = 0; k4 < KR; ++k4) {
        float4 xa = x0[k4];
        float4 xb = x0[KR + k4];
        float4 xc = x0[2 * KR + k4];
        float4 xd = x0[3 * KR + k4];
        float w0 = Wl[(4 * k4 + 0) * 64 + lane];
        float w1 = Wl[(4 * k4 + 1) * 64 + lane];
        float w2 = Wl[(4 * k4 + 2) * 64 + lane];
        float w3 = Wl[(4 * k4 + 3) * 64 + lane];
        acc0 = fmaf(xa.w, w3, fmaf(xa.z, w2, fmaf(xa.y, w1, fmaf(xa.x, w0, acc0))));
        acc1 = fmaf(xb.w, w3, fmaf(xb.z, w2, fmaf(xb.y, w1, fmaf(xb.x, w0, acc1))));
        acc2 = fmaf(xc.w, w3, fmaf(xc.z, w2, fmaf(xc.y, w1, fmaf(xc.x, w0, acc2))));
        acc3 = fmaf(xd.w, w3, fmaf(xd.z, w2, fmaf(xd.y, w1, fmaf(xd.x, w0, acc3))));
    }
    float accs[4] = {acc0, acc1, acc2, acc3};
    #pragma unroll
    for (int i = 0; i < 4; ++i) {
        float s1 = accs[i] * asj, s2 = accs[i] * adj;
        #pragma unroll
        for (int o = 32; o > 0; o >>= 1) {
            s1 += __shfl_xor(s1, o, 64);
            s2 += __shfl_xor(s2, o, 64);
        }
        H[(size_t)(n0 + i) * 64 + lane] = accs[i];
        if (lane == 0) { AS[n0 + i] = s1; AD[n0 + i] = s2; }
    }
}

// ---------------- per-dst aggregation, lane-parallel softmax ----------------
template<int RELU, int NORM>
__global__ __launch_bounds__(256) void k_agg(
    const int* __restrict__ esrc, const int* __restrict__ offs,
    const float* __restrict__ H, const float* __restrict__ AS,
    const float* __restrict__ AD, const float* __restrict__ bias,
    float* __restrict__ out, int N)
{
    __shared__ int2 sm[4][64];
    int gid = blockIdx.x * blockDim.x + threadIdx.x;
    int w = gid >> 6;
    int lane = gid & 63;
    int wid = threadIdx.x >> 6;
    if (w >= N) return;
    int beg = offs[w], end = offs[w + 1];
    int deg = end - beg;
    float bl = bias[lane];
    float val;
    if (deg == 0) {
        val = bl;
    } else if (deg <= 64) {
        float add = AD[w];
        int s = 0;
        float logit = -3.0e38f;
        if (lane < deg) {
            s = esrc[beg + lane];                 // coalesced
            float l0 = AS[s] + add;               // L2-hot 4B gather
            logit = (l0 > 0.f) ? l0 : 0.2f * l0;  // leaky_relu
        }
        float m = logit;
        #pragma unroll
        for (int o = 32; o > 0; o >>= 1) m = fmaxf(m, __shfl_xor(m, o, 64));
        float wg = (lane < deg) ? __expf(logit - m) : 0.f;
        float z = wg;
        #pragma unroll
        for (int o = 32; o > 0; o >>= 1) z += __shfl_xor(z, o, 64);
        sm[wid][lane] = make_int2(s, __float_as_int(wg));
        float acc = 0.f;
        const float* Hl = H + lane;
        for (int k = 0; k < deg; ++k) {
            int2 v = sm[wid][k];                  // LDS broadcast (src, weight)
            acc = fmaf(__int_as_float(v.y), Hl[(size_t)v.x * 64], acc);
        }
        val = acc / z + bl;
    } else {
        // fallback for degree > 64 (statistically never taken here)
        float add = AD[w];
        float m = -3.0e38f, z = 0.f, acc = 0.f;
        for (int i = beg; i < end; ++i) {
            int s = esrc[i];
            float l0 = AS[s] + add;
            l0 = (l0 > 0.f) ? l0 : 0.2f * l0;
            float mn = fmaxf(m, l0);
            float sc = __expf(m - mn);
            float wgt = __expf(l0 - mn);
            z = z * sc + wgt;
            acc = acc * sc + wgt * H[(size_t)s * 64 + lane];
            m = mn;
        }
        val = acc / z + bl;
    }
    if (RELU) val = fmaxf(val, 0.f);
    if (NORM) {
        float ss = val * val;
        #pragma unroll
        for (int o = 32; o > 0; o >>= 1) ss += __shfl_xor(ss, o, 64);
        val = val / fmaxf(sqrtf(ss), 1e-12f);
    }
    out[(size_t)w * 64 + lane] = val;
}

// ---------------- launch ----------------

extern "C" void kernel_launch(void* const* d_in, const int* in_sizes, int n_in,
                              void* d_out, int out_size, void* d_ws, size_t ws_size,
                              hipStream_t stream) {
    const float* x   = (const float*)d_in[0];
    const int*   ei  = (const int*)d_in[1];
    const float* W1  = (const float*)d_in[2];
    const float* as1 = (const float*)d_in[3];
    const float* ad1 = (const float*)d_in[4];
    const float* b1  = (const float*)d_in[5];
    const float* W2  = (const float*)d_in[6];
    const float* as2 = (const float*)d_in[7];
    const float* ad2 = (const float*)d_in[8];
    const float* b2  = (const float*)d_in[9];
    const int* src = ei;
    const int* dst = ei + NEDGES;

    char* ws = (char*)d_ws;
    size_t off = 0;
    auto alloc = [&](size_t bytes) -> void* {
        void* p = ws + off;
        off = (off + bytes + 255) & ~(size_t)255;
        return p;
    };
    float* H    = (float*)alloc((size_t)NNODES * 64 * 4);
    float* OUT1 = (float*)alloc((size_t)NNODES * 64 * 4);
    float* AS   = (float*)alloc((size_t)NNODES * 4);
    float* AD   = (float*)alloc((size_t)NNODES * 4);
    int* offs   = (int*)alloc((size_t)(NNODES + 1) * 4);
    int* deg    = (int*)alloc((size_t)NNODES * 4);
    int* cursor = (int*)alloc((size_t)NNODES * 4);
    int* esrc   = (int*)alloc((size_t)NEDGES * 4);
    int* partial= (int*)alloc(64 * 4);

    hipMemsetAsync(deg, 0, (size_t)NNODES * 4, stream);
    hipMemsetAsync(cursor, 0, (size_t)NNODES * 4, stream);

    // CSR build (dst identical for both layers)
    k_hist<<<(NEDGES + 255) / 256, 256, 0, stream>>>(dst, deg, NEDGES);
    int nb = (NNODES + 1023) / 1024;  // 49
    k_scan_block<<<nb, 1024, 0, stream>>>(deg, offs, partial, NNODES);
    k_scan_partial<<<1, 64, 0, stream>>>(partial, offs, nb, NNODES);
    k_scan_add<<<nb, 1024, 0, stream>>>(offs, partial, NNODES);
    k_scatter<<<(NEDGES + 255) / 256, 256, 0, stream>>>(src, dst, offs, cursor, esrc, NEDGES);

    // Layer 1
    k_gemm_att<128><<<(NNODES + 15) / 16, 256, 0, stream>>>(x, W1, as1, ad1, H, AS, AD, NNODES);
    k_agg<1, 0><<<((NNODES * 64) + 255) / 256, 256, 0, stream>>>(esrc, offs, H, AS, AD, b1, OUT1, NNODES);

    // Layer 2
    k_gemm_att<64><<<(NNODES + 15) / 16, 256, 0, stream>>>(OUT1, W2, as2, ad2, H, AS, AD, NNODES);
    k_agg<0, 1><<<((NNODES * 64) + 255) / 256, 256, 0, stream>>>(esrc, offs, H, AS, AD, b2, (float*)d_out, NNODES);
}

// Round 3
// 206.054 us; speedup vs baseline: 1.7547x; 1.6265x over previous
//
#include <hip/hip_runtime.h>
#include <math.h>

#define NNODES 50000
#define NEDGES 800000

// ---------------- CSR build ----------------

__global__ void k_hist(const int* __restrict__ dst, int* __restrict__ deg, int E) {
    int e = blockIdx.x * blockDim.x + threadIdx.x;
    if (e < E) atomicAdd(&deg[dst[e]], 1);
}

__global__ void k_scan_block(const int* __restrict__ deg, int* __restrict__ offs,
                             int* __restrict__ partial, int N) {
    __shared__ int tmp[1024];
    int t = threadIdx.x;
    int i = blockIdx.x * 1024 + t;
    int v = (i < N) ? deg[i] : 0;
    tmp[t] = v;
    __syncthreads();
    for (int off = 1; off < 1024; off <<= 1) {
        int u = (t >= off) ? tmp[t - off] : 0;
        __syncthreads();
        tmp[t] += u;
        __syncthreads();
    }
    if (i < N) offs[i] = tmp[t] - v;
    if (t == 1023) partial[blockIdx.x] = tmp[t];
}

__global__ void k_scan_partial(int* __restrict__ partial, int* __restrict__ offs,
                               int nb, int N) {
    int l = threadIdx.x;
    int v = (l < nb) ? partial[l] : 0;
    int incl = v;
    #pragma unroll
    for (int off = 1; off < 64; off <<= 1) {
        int u = __shfl_up(incl, off, 64);
        if (l >= off) incl += u;
    }
    if (l < nb) partial[l] = incl - v;
    if (l == 63) offs[N] = incl;
}

__global__ void k_scan_add(int* __restrict__ offs, const int* __restrict__ partial, int N) {
    int i = blockIdx.x * 1024 + threadIdx.x;
    if (i < N) offs[i] += partial[blockIdx.x];
}

__global__ void k_scatter(const int* __restrict__ src, const int* __restrict__ dst,
                          const int* __restrict__ offs, int* __restrict__ cursor,
                          int* __restrict__ esrc, int E) {
    int e = blockIdx.x * blockDim.x + threadIdx.x;
    if (e < E) {
        int d = dst[e];
        int pos = offs[d] + atomicAdd(&cursor[d], 1);
        esrc[pos] = src[e];
    }
}

// ---------------- tiled SGEMM + attention-logit epilogue ----------------
// 64x64 output tile per 256-thread block; 4x4 micro-tile per thread.
// Xs swizzled by (row>>2)&3 on the k4 index -> conflict-free 4-row ds_read_b128.

__device__ __forceinline__ void fma4(float4& a, float s, const float4& w) {
    a.x = fmaf(s, w.x, a.x);
    a.y = fmaf(s, w.y, a.y);
    a.z = fmaf(s, w.z, a.z);
    a.w = fmaf(s, w.w, a.w);
}

template<int K>
__global__ __launch_bounds__(256, 2) void k_gemm_att(
    const float* __restrict__ X, const float* __restrict__ W,
    const float* __restrict__ a_src, const float* __restrict__ a_dst,
    float* __restrict__ H, float* __restrict__ AS, float* __restrict__ AD, int N)
{
    constexpr int KF = K / 4;                 // float4 chunks per row
    constexpr int KFS = (K == 128) ? 5 : 4;   // log2(KF)
    __shared__ float Xs[64 * K];
    __shared__ float Ws[K * 64];
    int t = threadIdx.x;
    int n0 = blockIdx.x * 64;

    // stage W (whole matrix) -- coalesced
    const float4* W4 = (const float4*)W;
    #pragma unroll
    for (int f = t; f < K * 16; f += 256)
        ((float4*)Ws)[f] = W4[f];
    // stage X tile -- coalesced, k4-swizzled
    const float4* X4 = (const float4*)X;
    #pragma unroll
    for (int f = t; f < 64 * KF; f += 256) {
        int r = f >> KFS, k4 = f & (KF - 1);
        float4 v = {0.f, 0.f, 0.f, 0.f};
        if (n0 + r < N) v = X4[(size_t)(n0 + r) * KF + k4];
        ((float4*)&Xs[r * K])[k4 ^ ((r >> 2) & 3)] = v;
    }
    __syncthreads();

    int tr = t >> 4, tc = t & 15;
    int xi = tr & 3;  // swizzle key: rows tr*4..tr*4+3 all have (row>>2)&3 == tr&3
    const float4* xr0 = (const float4*)&Xs[(tr * 4 + 0) * K];
    const float4* xr1 = (const float4*)&Xs[(tr * 4 + 1) * K];
    const float4* xr2 = (const float4*)&Xs[(tr * 4 + 2) * K];
    const float4* xr3 = (const float4*)&Xs[(tr * 4 + 3) * K];
    float4 acc0 = {}, acc1 = {}, acc2 = {}, acc3 = {};

    #pragma unroll 2
    for (int k4 = 0; k4 < KF; ++k4) {
        int sl = k4 ^ xi;
        float4 x0 = xr0[sl], x1 = xr1[sl], x2 = xr2[sl], x3 = xr3[sl];
        float4 w0 = *(const float4*)&Ws[(k4 * 4 + 0) * 64 + tc * 4];
        float4 w1 = *(const float4*)&Ws[(k4 * 4 + 1) * 64 + tc * 4];
        float4 w2 = *(const float4*)&Ws[(k4 * 4 + 2) * 64 + tc * 4];
        float4 w3 = *(const float4*)&Ws[(k4 * 4 + 3) * 64 + tc * 4];
        fma4(acc0, x0.x, w0); fma4(acc0, x0.y, w1); fma4(acc0, x0.z, w2); fma4(acc0, x0.w, w3);
        fma4(acc1, x1.x, w0); fma4(acc1, x1.y, w1); fma4(acc1, x1.z, w2); fma4(acc1, x1.w, w3);
        fma4(acc2, x2.x, w0); fma4(acc2, x2.y, w1); fma4(acc2, x2.z, w2); fma4(acc2, x2.w, w3);
        fma4(acc3, x3.x, w0); fma4(acc3, x3.y, w1); fma4(acc3, x3.z, w2); fma4(acc3, x3.w, w3);
    }

    // epilogue: store H, compute per-row attention logits
    float4 asv = *(const float4*)&a_src[tc * 4];
    float4 adv = *(const float4*)&a_dst[tc * 4];
    float4 accs[4] = {acc0, acc1, acc2, acc3};
    #pragma unroll
    for (int i = 0; i < 4; ++i) {
        int row = n0 + tr * 4 + i;
        if (row < N) {
            float4 a = accs[i];
            float s1 = a.x * asv.x + a.y * asv.y + a.z * asv.z + a.w * asv.w;
            float s2 = a.x * adv.x + a.y * adv.y + a.z * adv.z + a.w * adv.w;
            #pragma unroll
            for (int o = 1; o < 16; o <<= 1) {
                s1 += __shfl_xor(s1, o, 64);
                s2 += __shfl_xor(s2, o, 64);
            }
            *(float4*)&H[(size_t)row * 64 + tc * 4] = a;
            if (tc == 0) { AS[row] = s1; AD[row] = s2; }
        }
    }
}

// ---------------- per-dst aggregation, lane-parallel softmax ----------------
template<int RELU, int NORM>
__global__ __launch_bounds__(256) void k_agg(
    const int* __restrict__ esrc, const int* __restrict__ offs,
    const float* __restrict__ H, const float* __restrict__ AS,
    const float* __restrict__ AD, const float* __restrict__ bias,
    float* __restrict__ out, int N)
{
    __shared__ int2 sm[4][64];
    int gid = blockIdx.x * blockDim.x + threadIdx.x;
    int w = gid >> 6;
    int lane = gid & 63;
    int wid = threadIdx.x >> 6;
    if (w >= N) return;
    int beg = offs[w], end = offs[w + 1];
    int deg = end - beg;
    float bl = bias[lane];
    float val;
    if (deg == 0) {
        val = bl;
    } else if (deg <= 64) {
        float add = AD[w];
        int s = 0;
        float logit = -3.0e38f;
        if (lane < deg) {
            s = esrc[beg + lane];                 // coalesced
            float l0 = AS[s] + add;               // cache-hot 4B gather
            logit = (l0 > 0.f) ? l0 : 0.2f * l0;  // leaky_relu
        }
        float m = logit;
        #pragma unroll
        for (int o = 32; o > 0; o >>= 1) m = fmaxf(m, __shfl_xor(m, o, 64));
        float wg = (lane < deg) ? __expf(logit - m) : 0.f;
        float z = wg;
        #pragma unroll
        for (int o = 32; o > 0; o >>= 1) z += __shfl_xor(z, o, 64);
        sm[wid][lane] = make_int2(s, __float_as_int(wg));
        float acc = 0.f;
        const float* Hl = H + lane;
        for (int k = 0; k < deg; ++k) {
            int2 v = sm[wid][k];                  // LDS broadcast (src, weight)
            acc = fmaf(__int_as_float(v.y), Hl[(size_t)v.x * 64], acc);
        }
        val = acc / z + bl;
    } else {
        float add = AD[w];
        float m = -3.0e38f, z = 0.f, acc = 0.f;
        for (int i = beg; i < end; ++i) {
            int s = esrc[i];
            float l0 = AS[s] + add;
            l0 = (l0 > 0.f) ? l0 : 0.2f * l0;
            float mn = fmaxf(m, l0);
            float sc = __expf(m - mn);
            float wgt = __expf(l0 - mn);
            z = z * sc + wgt;
            acc = acc * sc + wgt * H[(size_t)s * 64 + lane];
            m = mn;
        }
        val = acc / z + bl;
    }
    if (RELU) val = fmaxf(val, 0.f);
    if (NORM) {
        float ss = val * val;
        #pragma unroll
        for (int o = 32; o > 0; o >>= 1) ss += __shfl_xor(ss, o, 64);
        val = val / fmaxf(sqrtf(ss), 1e-12f);
    }
    out[(size_t)w * 64 + lane] = val;
}

// ---------------- launch ----------------

extern "C" void kernel_launch(void* const* d_in, const int* in_sizes, int n_in,
                              void* d_out, int out_size, void* d_ws, size_t ws_size,
                              hipStream_t stream) {
    const float* x   = (const float*)d_in[0];
    const int*   ei  = (const int*)d_in[1];
    const float* W1  = (const float*)d_in[2];
    const float* as1 = (const float*)d_in[3];
    const float* ad1 = (const float*)d_in[4];
    const float* b1  = (const float*)d_in[5];
    const float* W2  = (const float*)d_in[6];
    const float* as2 = (const float*)d_in[7];
    const float* ad2 = (const float*)d_in[8];
    const float* b2  = (const float*)d_in[9];
    const int* src = ei;
    const int* dst = ei + NEDGES;

    char* ws = (char*)d_ws;
    size_t off = 0;
    auto alloc = [&](size_t bytes) -> void* {
        void* p = ws + off;
        off = (off + bytes + 255) & ~(size_t)255;
        return p;
    };
    float* H    = (float*)alloc((size_t)NNODES * 64 * 4);
    float* OUT1 = (float*)alloc((size_t)NNODES * 64 * 4);
    float* AS   = (float*)alloc((size_t)NNODES * 4);
    float* AD   = (float*)alloc((size_t)NNODES * 4);
    int* offs   = (int*)alloc((size_t)(NNODES + 1) * 4);
    int* deg    = (int*)alloc((size_t)NNODES * 4);
    int* cursor = (int*)alloc((size_t)NNODES * 4);
    int* esrc   = (int*)alloc((size_t)NEDGES * 4);
    int* partial= (int*)alloc(64 * 4);

    hipMemsetAsync(deg, 0, (size_t)NNODES * 4, stream);
    hipMemsetAsync(cursor, 0, (size_t)NNODES * 4, stream);

    // CSR build (dst identical for both layers)
    k_hist<<<(NEDGES + 255) / 256, 256, 0, stream>>>(dst, deg, NEDGES);
    int nb = (NNODES + 1023) / 1024;  // 49
    k_scan_block<<<nb, 1024, 0, stream>>>(deg, offs, partial, NNODES);
    k_scan_partial<<<1, 64, 0, stream>>>(partial, offs, nb, NNODES);
    k_scan_add<<<nb, 1024, 0, stream>>>(offs, partial, NNODES);
    k_scatter<<<(NEDGES + 255) / 256, 256, 0, stream>>>(src, dst, offs, cursor, esrc, NEDGES);

    // Layer 1
    k_gemm_att<128><<<(NNODES + 63) / 64, 256, 0, stream>>>(x, W1, as1, ad1, H, AS, AD, NNODES);
    k_agg<1, 0><<<((NNODES * 64) + 255) / 256, 256, 0, stream>>>(esrc, offs, H, AS, AD, b1, OUT1, NNODES);

    // Layer 2
    k_gemm_att<64><<<(NNODES + 63) / 64, 256, 0, stream>>>(OUT1, W2, as2, ad2, H, AS, AD, NNODES);
    k_agg<0, 1><<<((NNODES * 64) + 255) / 256, 256, 0, stream>>>(esrc, offs, H, AS, AD, b2, (float*)d_out, NNODES);
}

// Round 4
// 178.183 us; speedup vs baseline: 2.0292x; 1.1564x over previous
//
#include <hip/hip_runtime.h>
#include <math.h>

#define NNODES 50000
#define NEDGES 800000

// ---------------- CSR build ----------------

__global__ void k_zero(int* __restrict__ p, int n) {
    int i = blockIdx.x * blockDim.x + threadIdx.x;
    if (i < n) p[i] = 0;
}

// histogram + per-edge rank in one atomic pass
__global__ void k_hist_rank(const int* __restrict__ dst, int* __restrict__ deg,
                            int* __restrict__ erank, int E) {
    int e = blockIdx.x * blockDim.x + threadIdx.x;
    if (e < E) erank[e] = atomicAdd(&deg[dst[e]], 1);
}

__global__ void k_scan_block(const int* __restrict__ deg, int* __restrict__ offs,
                             int* __restrict__ partial, int N) {
    __shared__ int tmp[1024];
    int t = threadIdx.x;
    int i = blockIdx.x * 1024 + t;
    int v = (i < N) ? deg[i] : 0;
    tmp[t] = v;
    __syncthreads();
    for (int off = 1; off < 1024; off <<= 1) {
        int u = (t >= off) ? tmp[t - off] : 0;
        __syncthreads();
        tmp[t] += u;
        __syncthreads();
    }
    if (i < N) offs[i] = tmp[t] - v;
    if (t == 1023) partial[blockIdx.x] = tmp[t];
}

__global__ void k_scan_partial(int* __restrict__ partial, int* __restrict__ offs,
                               int nb, int N) {
    int l = threadIdx.x;
    int v = (l < nb) ? partial[l] : 0;
    int incl = v;
    #pragma unroll
    for (int off = 1; off < 64; off <<= 1) {
        int u = __shfl_up(incl, off, 64);
        if (l >= off) incl += u;
    }
    if (l < nb) partial[l] = incl - v;
    if (l == 63) offs[N] = incl;
}

__global__ void k_scan_add(int* __restrict__ offs, const int* __restrict__ partial, int N) {
    int i = blockIdx.x * 1024 + threadIdx.x;
    if (i < N) offs[i] += partial[blockIdx.x];
}

// atomic-free scatter using precomputed ranks
__global__ void k_scatter(const int* __restrict__ src, const int* __restrict__ dst,
                          const int* __restrict__ offs, const int* __restrict__ erank,
                          int* __restrict__ esrc, int E) {
    int e = blockIdx.x * blockDim.x + threadIdx.x;
    if (e < E) {
        esrc[offs[dst[e]] + erank[e]] = src[e];
    }
}

// ---------------- tiled SGEMM + attention-logit epilogue ----------------
// 64x64 output tile per 256-thread block; 4x4 micro-tile per thread.
// Xs swizzled by (row>>2)&3 on the k4 index -> conflict-free 4-row ds_read_b128.

__device__ __forceinline__ void fma4(float4& a, float s, const float4& w) {
    a.x = fmaf(s, w.x, a.x);
    a.y = fmaf(s, w.y, a.y);
    a.z = fmaf(s, w.z, a.z);
    a.w = fmaf(s, w.w, a.w);
}

template<int K>
__global__ __launch_bounds__(256, 2) void k_gemm_att(
    const float* __restrict__ X, const float* __restrict__ W,
    const float* __restrict__ a_src, const float* __restrict__ a_dst,
    float* __restrict__ H, float* __restrict__ AS, float* __restrict__ AD, int N)
{
    constexpr int KF = K / 4;                 // float4 chunks per row
    constexpr int KFS = (K == 128) ? 5 : 4;   // log2(KF)
    __shared__ float Xs[64 * K];
    __shared__ float Ws[K * 64];
    int t = threadIdx.x;
    int n0 = blockIdx.x * 64;

    const float4* W4 = (const float4*)W;
    #pragma unroll
    for (int f = t; f < K * 16; f += 256)
        ((float4*)Ws)[f] = W4[f];
    const float4* X4 = (const float4*)X;
    #pragma unroll
    for (int f = t; f < 64 * KF; f += 256) {
        int r = f >> KFS, k4 = f & (KF - 1);
        float4 v = {0.f, 0.f, 0.f, 0.f};
        if (n0 + r < N) v = X4[(size_t)(n0 + r) * KF + k4];
        ((float4*)&Xs[r * K])[k4 ^ ((r >> 2) & 3)] = v;
    }
    __syncthreads();

    int tr = t >> 4, tc = t & 15;
    int xi = tr & 3;
    const float4* xr0 = (const float4*)&Xs[(tr * 4 + 0) * K];
    const float4* xr1 = (const float4*)&Xs[(tr * 4 + 1) * K];
    const float4* xr2 = (const float4*)&Xs[(tr * 4 + 2) * K];
    const float4* xr3 = (const float4*)&Xs[(tr * 4 + 3) * K];
    float4 acc0 = {}, acc1 = {}, acc2 = {}, acc3 = {};

    #pragma unroll 2
    for (int k4 = 0; k4 < KF; ++k4) {
        int sl = k4 ^ xi;
        float4 x0 = xr0[sl], x1 = xr1[sl], x2 = xr2[sl], x3 = xr3[sl];
        float4 w0 = *(const float4*)&Ws[(k4 * 4 + 0) * 64 + tc * 4];
        float4 w1 = *(const float4*)&Ws[(k4 * 4 + 1) * 64 + tc * 4];
        float4 w2 = *(const float4*)&Ws[(k4 * 4 + 2) * 64 + tc * 4];
        float4 w3 = *(const float4*)&Ws[(k4 * 4 + 3) * 64 + tc * 4];
        fma4(acc0, x0.x, w0); fma4(acc0, x0.y, w1); fma4(acc0, x0.z, w2); fma4(acc0, x0.w, w3);
        fma4(acc1, x1.x, w0); fma4(acc1, x1.y, w1); fma4(acc1, x1.z, w2); fma4(acc1, x1.w, w3);
        fma4(acc2, x2.x, w0); fma4(acc2, x2.y, w1); fma4(acc2, x2.z, w2); fma4(acc2, x2.w, w3);
        fma4(acc3, x3.x, w0); fma4(acc3, x3.y, w1); fma4(acc3, x3.z, w2); fma4(acc3, x3.w, w3);
    }

    float4 asv = *(const float4*)&a_src[tc * 4];
    float4 adv = *(const float4*)&a_dst[tc * 4];
    float4 accs[4] = {acc0, acc1, acc2, acc3};
    #pragma unroll
    for (int i = 0; i < 4; ++i) {
        int row = n0 + tr * 4 + i;
        if (row < N) {
            float4 a = accs[i];
            float s1 = a.x * asv.x + a.y * asv.y + a.z * asv.z + a.w * asv.w;
            float s2 = a.x * adv.x + a.y * adv.y + a.z * adv.z + a.w * adv.w;
            #pragma unroll
            for (int o = 1; o < 16; o <<= 1) {
                s1 += __shfl_xor(s1, o, 64);
                s2 += __shfl_xor(s2, o, 64);
            }
            *(float4*)&H[(size_t)row * 64 + tc * 4] = a;
            if (tc == 0) { AS[row] = s1; AD[row] = s2; }
        }
    }
}

// ---------------- per-dst aggregation, lane-parallel softmax ----------------
template<int RELU, int NORM>
__global__ __launch_bounds__(256) void k_agg(
    const int* __restrict__ esrc, const int* __restrict__ offs,
    const float* __restrict__ H, const float* __restrict__ AS,
    const float* __restrict__ AD, const float* __restrict__ bias,
    float* __restrict__ out, int N)
{
    __shared__ int2 sm[4][64];
    int gid = blockIdx.x * blockDim.x + threadIdx.x;
    int w = gid >> 6;
    int lane = gid & 63;
    int wid = threadIdx.x >> 6;
    if (w >= N) return;
    int beg = offs[w], end = offs[w + 1];
    int deg = end - beg;
    float bl = bias[lane];
    float val;
    if (deg == 0) {
        val = bl;
    } else if (deg <= 64) {
        float add = AD[w];
        int s = 0;
        float logit = -3.0e38f;
        if (lane < deg) {
            s = esrc[beg + lane];                 // coalesced
            float l0 = AS[s] + add;               // cache-hot 4B gather
            logit = (l0 > 0.f) ? l0 : 0.2f * l0;  // leaky_relu
        }
        float m = logit;
        #pragma unroll
        for (int o = 32; o > 0; o >>= 1) m = fmaxf(m, __shfl_xor(m, o, 64));
        float wg = (lane < deg) ? __expf(logit - m) : 0.f;
        float z = wg;
        #pragma unroll
        for (int o = 32; o > 0; o >>= 1) z += __shfl_xor(z, o, 64);
        sm[wid][lane] = make_int2(s, __float_as_int(wg));
        float acc = 0.f;
        const float* Hl = H + lane;
        for (int k = 0; k < deg; ++k) {
            int2 v = sm[wid][k];                  // LDS broadcast (src, weight)
            acc = fmaf(__int_as_float(v.y), Hl[(size_t)v.x * 64], acc);
        }
        val = acc / z + bl;
    } else {
        float add = AD[w];
        float m = -3.0e38f, z = 0.f, acc = 0.f;
        for (int i = beg; i < end; ++i) {
            int s = esrc[i];
            float l0 = AS[s] + add;
            l0 = (l0 > 0.f) ? l0 : 0.2f * l0;
            float mn = fmaxf(m, l0);
            float sc = __expf(m - mn);
            float wgt = __expf(l0 - mn);
            z = z * sc + wgt;
            acc = acc * sc + wgt * H[(size_t)s * 64 + lane];
            m = mn;
        }
        val = acc / z + bl;
    }
    if (RELU) val = fmaxf(val, 0.f);
    if (NORM) {
        float ss = val * val;
        #pragma unroll
        for (int o = 32; o > 0; o >>= 1) ss += __shfl_xor(ss, o, 64);
        val = val / fmaxf(sqrtf(ss), 1e-12f);
    }
    out[(size_t)w * 64 + lane] = val;
}

// ---------------- launch ----------------

extern "C" void kernel_launch(void* const* d_in, const int* in_sizes, int n_in,
                              void* d_out, int out_size, void* d_ws, size_t ws_size,
                              hipStream_t stream) {
    const float* x   = (const float*)d_in[0];
    const int*   ei  = (const int*)d_in[1];
    const float* W1  = (const float*)d_in[2];
    const float* as1 = (const float*)d_in[3];
    const float* ad1 = (const float*)d_in[4];
    const float* b1  = (const float*)d_in[5];
    const float* W2  = (const float*)d_in[6];
    const float* as2 = (const float*)d_in[7];
    const float* ad2 = (const float*)d_in[8];
    const float* b2  = (const float*)d_in[9];
    const int* src = ei;
    const int* dst = ei + NEDGES;

    char* ws = (char*)d_ws;
    size_t off = 0;
    auto alloc = [&](size_t bytes) -> void* {
        void* p = ws + off;
        off = (off + bytes + 255) & ~(size_t)255;
        return p;
    };
    float* H    = (float*)alloc((size_t)NNODES * 64 * 4);
    float* OUT1 = (float*)alloc((size_t)NNODES * 64 * 4);
    float* AS   = (float*)alloc((size_t)NNODES * 4);
    float* AD   = (float*)alloc((size_t)NNODES * 4);
    int* offs   = (int*)alloc((size_t)(NNODES + 1) * 4);
    int* deg    = (int*)alloc((size_t)NNODES * 4);
    int* erank  = (int*)alloc((size_t)NEDGES * 4);
    int* esrc   = (int*)alloc((size_t)NEDGES * 4);
    int* partial= (int*)alloc(64 * 4);

    // CSR build (dst identical for both layers)
    k_zero<<<(NNODES + 255) / 256, 256, 0, stream>>>(deg, NNODES);
    k_hist_rank<<<(NEDGES + 255) / 256, 256, 0, stream>>>(dst, deg, erank, NEDGES);
    int nb = (NNODES + 1023) / 1024;  // 49
    k_scan_block<<<nb, 1024, 0, stream>>>(deg, offs, partial, NNODES);
    k_scan_partial<<<1, 64, 0, stream>>>(partial, offs, nb, NNODES);
    k_scan_add<<<nb, 1024, 0, stream>>>(offs, partial, NNODES);
    k_scatter<<<(NEDGES + 255) / 256, 256, 0, stream>>>(src, dst, offs, erank, esrc, NEDGES);

    // Layer 1
    k_gemm_att<128><<<(NNODES + 63) / 64, 256, 0, stream>>>(x, W1, as1, ad1, H, AS, AD, NNODES);
    k_agg<1, 0><<<((NNODES * 64) + 255) / 256, 256, 0, stream>>>(esrc, offs, H, AS, AD, b1, OUT1, NNODES);

    // Layer 2
    k_gemm_att<64><<<(NNODES + 63) / 64, 256, 0, stream>>>(OUT1, W2, as2, ad2, H, AS, AD, NNODES);
    k_agg<0, 1><<<((NNODES * 64) + 255) / 256, 256, 0, stream>>>(esrc, offs, H, AS, AD, b2, (float*)d_out, NNODES);
}

// Round 5
// 149.832 us; speedup vs baseline: 2.4132x; 1.1892x over previous
//
#include <hip/hip_runtime.h>
#include <math.h>

#define NNODES 50000
#define NEDGES 800000
#define NBUCK 256
#define EPB 2048
#define NBLK1 ((NEDGES + EPB - 1) / EPB)      // 391
#define SCANL (NBUCK * NBLK1)                  // 100096
#define SCANB ((SCANL + 1023) / 1024)          // 98

// ---------------- CSR build: two-level bucket sort, LDS atomics only ----------------

// per-block coarse histogram (dst>>8), bucket-major output
__global__ __launch_bounds__(256) void k_bcount(const int* __restrict__ dst,
                                                int* __restrict__ bcnt) {
    __shared__ int h[NBUCK];
    int t = threadIdx.x, b = blockIdx.x;
    h[t] = 0;
    __syncthreads();
    int beg = b * EPB, end = min(beg + EPB, NEDGES);
    for (int e = beg + t; e < end; e += 256) atomicAdd(&h[dst[e] >> 8], 1);
    __syncthreads();
    bcnt[t * NBLK1 + b] = h[t];
}

// generic hierarchical exclusive scan (1024/block)
__global__ void k_scan_block(const int* __restrict__ in, int* __restrict__ out,
                             int* __restrict__ partial, int n) {
    __shared__ int tmp[1024];
    int t = threadIdx.x;
    int i = blockIdx.x * 1024 + t;
    int v = (i < n) ? in[i] : 0;
    tmp[t] = v;
    __syncthreads();
    for (int off = 1; off < 1024; off <<= 1) {
        int u = (t >= off) ? tmp[t - off] : 0;
        __syncthreads();
        tmp[t] += u;
        __syncthreads();
    }
    if (i < n) out[i] = tmp[t] - v;
    if (t == 1023) partial[blockIdx.x] = tmp[t];
}

__global__ void k_scan_add(int* __restrict__ out, const int* __restrict__ partial, int n) {
    int i = blockIdx.x * 1024 + threadIdx.x;
    if (i < n) out[i] += partial[blockIdx.x];
}

// atomic-free (global) bucket scatter; LDS cursors seeded from scanned offsets
__global__ __launch_bounds__(256) void k_bscatter(const int* __restrict__ src,
                                                  const int* __restrict__ dst,
                                                  const int* __restrict__ boffs,
                                                  int2* __restrict__ ep) {
    __shared__ int cur[NBUCK];
    int t = threadIdx.x, b = blockIdx.x;
    cur[t] = boffs[t * NBLK1 + b];
    __syncthreads();
    int beg = b * EPB, end = min(beg + EPB, NEDGES);
    for (int e = beg + t; e < end; e += 256) {
        int d = dst[e];
        int pos = atomicAdd(&cur[d >> 8], 1);
        ep[pos] = make_int2(d, src[e]);
    }
}

// per-bucket fine CSR: LDS histogram + LDS scan -> offs[] and dst-sorted esrc[]
__global__ __launch_bounds__(256) void k_fine(const int2* __restrict__ ep,
                                              const int* __restrict__ boffs,
                                              int* __restrict__ offs,
                                              int* __restrict__ esrc) {
    __shared__ int h[NBUCK];
    __shared__ int cur[NBUCK];
    int t = threadIdx.x, buck = blockIdx.x;
    int base = boffs[buck * NBLK1];
    int endp = (buck == NBUCK - 1) ? NEDGES : boffs[(buck + 1) * NBLK1];
    h[t] = 0;
    __syncthreads();
    for (int i = base + t; i < endp; i += 256) atomicAdd(&h[ep[i].x & 255], 1);
    __syncthreads();
    int v = h[t];
    for (int off = 1; off < 256; off <<= 1) {
        int u = (t >= off) ? h[t - off] : 0;
        __syncthreads();
        h[t] += u;
        __syncthreads();
    }
    int excl = h[t] - v;                      // exclusive prefix within bucket
    int node = buck * 256 + t;
    if (node <= NNODES) offs[node] = base + excl;
    cur[t] = base + excl;
    __syncthreads();
    for (int i = base + t; i < endp; i += 256) {
        int2 p = ep[i];
        int pos = atomicAdd(&cur[p.x & 255], 1);
        esrc[pos] = p.y;
    }
}

// ---------------- tiled SGEMM + attention-logit epilogue ----------------

__device__ __forceinline__ void fma4(float4& a, float s, const float4& w) {
    a.x = fmaf(s, w.x, a.x);
    a.y = fmaf(s, w.y, a.y);
    a.z = fmaf(s, w.z, a.z);
    a.w = fmaf(s, w.w, a.w);
}

template<int K>
__global__ __launch_bounds__(256, 2) void k_gemm_att(
    const float* __restrict__ X, const float* __restrict__ W,
    const float* __restrict__ a_src, const float* __restrict__ a_dst,
    float* __restrict__ H, float* __restrict__ AS, float* __restrict__ AD, int N)
{
    constexpr int KF = K / 4;
    constexpr int KFS = (K == 128) ? 5 : 4;
    __shared__ float Xs[64 * K];
    __shared__ float Ws[K * 64];
    int t = threadIdx.x;
    int n0 = blockIdx.x * 64;

    const float4* W4 = (const float4*)W;
    #pragma unroll
    for (int f = t; f < K * 16; f += 256)
        ((float4*)Ws)[f] = W4[f];
    const float4* X4 = (const float4*)X;
    #pragma unroll
    for (int f = t; f < 64 * KF; f += 256) {
        int r = f >> KFS, k4 = f & (KF - 1);
        float4 v = {0.f, 0.f, 0.f, 0.f};
        if (n0 + r < N) v = X4[(size_t)(n0 + r) * KF + k4];
        ((float4*)&Xs[r * K])[k4 ^ ((r >> 2) & 3)] = v;
    }
    __syncthreads();

    int tr = t >> 4, tc = t & 15;
    int xi = tr & 3;
    const float4* xr0 = (const float4*)&Xs[(tr * 4 + 0) * K];
    const float4* xr1 = (const float4*)&Xs[(tr * 4 + 1) * K];
    const float4* xr2 = (const float4*)&Xs[(tr * 4 + 2) * K];
    const float4* xr3 = (const float4*)&Xs[(tr * 4 + 3) * K];
    float4 acc0 = {}, acc1 = {}, acc2 = {}, acc3 = {};

    #pragma unroll 2
    for (int k4 = 0; k4 < KF; ++k4) {
        int sl = k4 ^ xi;
        float4 x0 = xr0[sl], x1 = xr1[sl], x2 = xr2[sl], x3 = xr3[sl];
        float4 w0 = *(const float4*)&Ws[(k4 * 4 + 0) * 64 + tc * 4];
        float4 w1 = *(const float4*)&Ws[(k4 * 4 + 1) * 64 + tc * 4];
        float4 w2 = *(const float4*)&Ws[(k4 * 4 + 2) * 64 + tc * 4];
        float4 w3 = *(const float4*)&Ws[(k4 * 4 + 3) * 64 + tc * 4];
        fma4(acc0, x0.x, w0); fma4(acc0, x0.y, w1); fma4(acc0, x0.z, w2); fma4(acc0, x0.w, w3);
        fma4(acc1, x1.x, w0); fma4(acc1, x1.y, w1); fma4(acc1, x1.z, w2); fma4(acc1, x1.w, w3);
        fma4(acc2, x2.x, w0); fma4(acc2, x2.y, w1); fma4(acc2, x2.z, w2); fma4(acc2, x2.w, w3);
        fma4(acc3, x3.x, w0); fma4(acc3, x3.y, w1); fma4(acc3, x3.z, w2); fma4(acc3, x3.w, w3);
    }

    float4 asv = *(const float4*)&a_src[tc * 4];
    float4 adv = *(const float4*)&a_dst[tc * 4];
    float4 accs[4] = {acc0, acc1, acc2, acc3};
    #pragma unroll
    for (int i = 0; i < 4; ++i) {
        int row = n0 + tr * 4 + i;
        if (row < N) {
            float4 a = accs[i];
            float s1 = a.x * asv.x + a.y * asv.y + a.z * asv.z + a.w * asv.w;
            float s2 = a.x * adv.x + a.y * adv.y + a.z * adv.z + a.w * adv.w;
            #pragma unroll
            for (int o = 1; o < 16; o <<= 1) {
                s1 += __shfl_xor(s1, o, 64);
                s2 += __shfl_xor(s2, o, 64);
            }
            *(float4*)&H[(size_t)row * 64 + tc * 4] = a;
            if (tc == 0) { AS[row] = s1; AD[row] = s2; }
        }
    }
}

// ---------------- per-dst aggregation, lane-parallel softmax ----------------
template<int RELU, int NORM>
__global__ __launch_bounds__(256) void k_agg(
    const int* __restrict__ esrc, const int* __restrict__ offs,
    const float* __restrict__ H, const float* __restrict__ AS,
    const float* __restrict__ AD, const float* __restrict__ bias,
    float* __restrict__ out, int N)
{
    __shared__ int2 sm[4][64];
    int gid = blockIdx.x * blockDim.x + threadIdx.x;
    int w = gid >> 6;
    int lane = gid & 63;
    int wid = threadIdx.x >> 6;
    if (w >= N) return;
    int beg = offs[w], end = offs[w + 1];
    int deg = end - beg;
    float bl = bias[lane];
    float val;
    if (deg == 0) {
        val = bl;
    } else if (deg <= 64) {
        float add = AD[w];
        int s = 0;
        float logit = -3.0e38f;
        if (lane < deg) {
            s = esrc[beg + lane];
            float l0 = AS[s] + add;
            logit = (l0 > 0.f) ? l0 : 0.2f * l0;
        }
        float m = logit;
        #pragma unroll
        for (int o = 32; o > 0; o >>= 1) m = fmaxf(m, __shfl_xor(m, o, 64));
        float wg = (lane < deg) ? __expf(logit - m) : 0.f;
        float z = wg;
        #pragma unroll
        for (int o = 32; o > 0; o >>= 1) z += __shfl_xor(z, o, 64);
        sm[wid][lane] = make_int2(s, __float_as_int(wg));
        float acc = 0.f;
        const float* Hl = H + lane;
        for (int k = 0; k < deg; ++k) {
            int2 v = sm[wid][k];
            acc = fmaf(__int_as_float(v.y), Hl[(size_t)v.x * 64], acc);
        }
        val = acc / z + bl;
    } else {
        float add = AD[w];
        float m = -3.0e38f, z = 0.f, acc = 0.f;
        for (int i = beg; i < end; ++i) {
            int s = esrc[i];
            float l0 = AS[s] + add;
            l0 = (l0 > 0.f) ? l0 : 0.2f * l0;
            float mn = fmaxf(m, l0);
            float sc = __expf(m - mn);
            float wgt = __expf(l0 - mn);
            z = z * sc + wgt;
            acc = acc * sc + wgt * H[(size_t)s * 64 + lane];
            m = mn;
        }
        val = acc / z + bl;
    }
    if (RELU) val = fmaxf(val, 0.f);
    if (NORM) {
        float ss = val * val;
        #pragma unroll
        for (int o = 32; o > 0; o >>= 1) ss += __shfl_xor(ss, o, 64);
        val = val / fmaxf(sqrtf(ss), 1e-12f);
    }
    out[(size_t)w * 64 + lane] = val;
}

// ---------------- launch ----------------

extern "C" void kernel_launch(void* const* d_in, const int* in_sizes, int n_in,
                              void* d_out, int out_size, void* d_ws, size_t ws_size,
                              hipStream_t stream) {
    const float* x   = (const float*)d_in[0];
    const int*   ei  = (const int*)d_in[1];
    const float* W1  = (const float*)d_in[2];
    const float* as1 = (const float*)d_in[3];
    const float* ad1 = (const float*)d_in[4];
    const float* b1  = (const float*)d_in[5];
    const float* W2  = (const float*)d_in[6];
    const float* as2 = (const float*)d_in[7];
    const float* ad2 = (const float*)d_in[8];
    const float* b2  = (const float*)d_in[9];
    const int* src = ei;
    const int* dst = ei + NEDGES;

    char* ws = (char*)d_ws;
    size_t off = 0;
    auto alloc = [&](size_t bytes) -> void* {
        void* p = ws + off;
        off = (off + bytes + 255) & ~(size_t)255;
        return p;
    };
    float* H     = (float*)alloc((size_t)NNODES * 64 * 4);
    float* OUT1  = (float*)alloc((size_t)NNODES * 64 * 4);
    float* AS    = (float*)alloc((size_t)NNODES * 4);
    float* AD    = (float*)alloc((size_t)NNODES * 4);
    int*   offs  = (int*)alloc((size_t)(NNODES + 1) * 4);
    int2*  ep    = (int2*)alloc((size_t)NEDGES * 8);
    int*   esrc  = (int*)alloc((size_t)NEDGES * 4);
    int*   bcnt  = (int*)alloc((size_t)SCANL * 4);
    int*   boffs = (int*)alloc((size_t)SCANL * 4);
    int*   part1 = (int*)alloc((size_t)SCANB * 4);
    int*   part1e= (int*)alloc((size_t)SCANB * 4);
    int*   part2 = (int*)alloc(4);

    // CSR build (dst identical for both layers) — no global atomics
    k_bcount<<<NBLK1, 256, 0, stream>>>(dst, bcnt);
    k_scan_block<<<SCANB, 1024, 0, stream>>>(bcnt, boffs, part1, SCANL);
    k_scan_block<<<1, 1024, 0, stream>>>(part1, part1e, part2, SCANB);
    k_scan_add<<<SCANB, 1024, 0, stream>>>(boffs, part1e, SCANL);
    k_bscatter<<<NBLK1, 256, 0, stream>>>(src, dst, boffs, ep);
    k_fine<<<NBUCK, 256, 0, stream>>>(ep, boffs, offs, esrc);

    // Layer 1
    k_gemm_att<128><<<(NNODES + 63) / 64, 256, 0, stream>>>(x, W1, as1, ad1, H, AS, AD, NNODES);
    k_agg<1, 0><<<((NNODES * 64) + 255) / 256, 256, 0, stream>>>(esrc, offs, H, AS, AD, b1, OUT1, NNODES);

    // Layer 2
    k_gemm_att<64><<<(NNODES + 63) / 64, 256, 0, stream>>>(OUT1, W2, as2, ad2, H, AS, AD, NNODES);
    k_agg<0, 1><<<((NNODES * 64) + 255) / 256, 256, 0, stream>>>(esrc, offs, H, AS, AD, b2, (float*)d_out, NNODES);
}

// Round 6
// 137.948 us; speedup vs baseline: 2.6210x; 1.0861x over previous
//
#include <hip/hip_runtime.h>
#include <hip/hip_fp16.h>
#include <math.h>

#define NNODES 50000
#define NEDGES 800000
#define NBUCK 256
#define EPB 4096
#define NBLK1 ((NEDGES + EPB - 1) / EPB)      // 196
#define SCANL (NBUCK * NBLK1)                  // 50176
#define SCANB ((SCANL + 1023) / 1024)          // 49

// ---------------- CSR build: two-level bucket sort, LDS atomics only ----------------

__global__ __launch_bounds__(256) void k_bcount(const int* __restrict__ dst,
                                                int* __restrict__ bcnt) {
    __shared__ int h[NBUCK];
    int t = threadIdx.x, b = blockIdx.x;
    h[t] = 0;
    __syncthreads();
    int beg = b * EPB, end = min(beg + EPB, NEDGES);
    for (int e = beg + t; e < end; e += 256) atomicAdd(&h[dst[e] >> 8], 1);
    __syncthreads();
    bcnt[t * NBLK1 + b] = h[t];
}

// hierarchical exclusive scan, level 1 (1024/block)
__global__ void k_scan_block(const int* __restrict__ in, int* __restrict__ out,
                             int* __restrict__ partial, int n) {
    __shared__ int tmp[1024];
    int t = threadIdx.x;
    int i = blockIdx.x * 1024 + t;
    int v = (i < n) ? in[i] : 0;
    tmp[t] = v;
    __syncthreads();
    for (int off = 1; off < 1024; off <<= 1) {
        int u = (t >= off) ? tmp[t - off] : 0;
        __syncthreads();
        tmp[t] += u;
        __syncthreads();
    }
    if (i < n) out[i] = tmp[t] - v;
    if (t == 1023) partial[blockIdx.x] = tmp[t];
}

// level 2: exclusive scan of <=64 partials in-place (single wave)
__global__ void k_scan_partial(int* __restrict__ partial, int nb) {
    int l = threadIdx.x;
    int v = (l < nb) ? partial[l] : 0;
    int incl = v;
    #pragma unroll
    for (int off = 1; off < 64; off <<= 1) {
        int u = __shfl_up(incl, off, 64);
        if (l >= off) incl += u;
    }
    if (l < nb) partial[l] = incl - v;
}

// bucket scatter; LDS cursors seeded from scanned offsets (+fused level-2 add)
__global__ __launch_bounds__(256) void k_bscatter(const int* __restrict__ src,
                                                  const int* __restrict__ dst,
                                                  const int* __restrict__ boffs,
                                                  const int* __restrict__ partial,
                                                  int2* __restrict__ ep) {
    __shared__ int cur[NBUCK];
    int t = threadIdx.x, b = blockIdx.x;
    int idx = t * NBLK1 + b;
    cur[t] = boffs[idx] + partial[idx >> 10];
    __syncthreads();
    int beg = b * EPB, end = min(beg + EPB, NEDGES);
    for (int e = beg + t; e < end; e += 256) {
        int d = dst[e];
        int pos = atomicAdd(&cur[d >> 8], 1);
        ep[pos] = make_int2(d, src[e]);
    }
}

// per-bucket fine CSR: LDS histogram + LDS scan -> offs[] and dst-sorted esrc[]
__global__ __launch_bounds__(256) void k_fine(const int2* __restrict__ ep,
                                              const int* __restrict__ boffs,
                                              const int* __restrict__ partial,
                                              int* __restrict__ offs,
                                              int* __restrict__ esrc) {
    __shared__ int h[NBUCK];
    __shared__ int cur[NBUCK];
    int t = threadIdx.x, buck = blockIdx.x;
    int bi = buck * NBLK1;
    int base = boffs[bi] + partial[bi >> 10];
    int endp;
    if (buck == NBUCK - 1) endp = NEDGES;
    else {
        int ei2 = (buck + 1) * NBLK1;
        endp = boffs[ei2] + partial[ei2 >> 10];
    }
    h[t] = 0;
    __syncthreads();
    for (int i = base + t; i < endp; i += 256) atomicAdd(&h[ep[i].x & 255], 1);
    __syncthreads();
    int v = h[t];
    for (int off = 1; off < 256; off <<= 1) {
        int u = (t >= off) ? h[t - off] : 0;
        __syncthreads();
        h[t] += u;
        __syncthreads();
    }
    int excl = h[t] - v;
    int node = buck * 256 + t;
    if (node <= NNODES) offs[node] = base + excl;
    cur[t] = base + excl;
    __syncthreads();
    for (int i = base + t; i < endp; i += 256) {
        int2 p = ep[i];
        int pos = atomicAdd(&cur[p.x & 255], 1);
        esrc[pos] = p.y;
    }
}

// ---------------- tiled SGEMM + attention-logit epilogue (fp16 H out) ----------------

__device__ __forceinline__ void fma4(float4& a, float s, const float4& w) {
    a.x = fmaf(s, w.x, a.x);
    a.y = fmaf(s, w.y, a.y);
    a.z = fmaf(s, w.z, a.z);
    a.w = fmaf(s, w.w, a.w);
}

template<int K>
__global__ __launch_bounds__(256, 2) void k_gemm_att(
    const float* __restrict__ X, const float* __restrict__ W,
    const float* __restrict__ a_src, const float* __restrict__ a_dst,
    __half* __restrict__ H, float* __restrict__ AS, float* __restrict__ AD, int N)
{
    constexpr int KF = K / 4;
    constexpr int KFS = (K == 128) ? 5 : 4;
    __shared__ float Xs[64 * K];
    __shared__ float Ws[K * 64];
    int t = threadIdx.x;
    int n0 = blockIdx.x * 64;

    const float4* W4 = (const float4*)W;
    #pragma unroll
    for (int f = t; f < K * 16; f += 256)
        ((float4*)Ws)[f] = W4[f];
    const float4* X4 = (const float4*)X;
    #pragma unroll
    for (int f = t; f < 64 * KF; f += 256) {
        int r = f >> KFS, k4 = f & (KF - 1);
        float4 v = {0.f, 0.f, 0.f, 0.f};
        if (n0 + r < N) v = X4[(size_t)(n0 + r) * KF + k4];
        ((float4*)&Xs[r * K])[k4 ^ ((r >> 2) & 3)] = v;
    }
    __syncthreads();

    int tr = t >> 4, tc = t & 15;
    int xi = tr & 3;
    const float4* xr0 = (const float4*)&Xs[(tr * 4 + 0) * K];
    const float4* xr1 = (const float4*)&Xs[(tr * 4 + 1) * K];
    const float4* xr2 = (const float4*)&Xs[(tr * 4 + 2) * K];
    const float4* xr3 = (const float4*)&Xs[(tr * 4 + 3) * K];
    float4 acc0 = {}, acc1 = {}, acc2 = {}, acc3 = {};

    #pragma unroll 2
    for (int k4 = 0; k4 < KF; ++k4) {
        int sl = k4 ^ xi;
        float4 x0 = xr0[sl], x1 = xr1[sl], x2 = xr2[sl], x3 = xr3[sl];
        float4 w0 = *(const float4*)&Ws[(k4 * 4 + 0) * 64 + tc * 4];
        float4 w1 = *(const float4*)&Ws[(k4 * 4 + 1) * 64 + tc * 4];
        float4 w2 = *(const float4*)&Ws[(k4 * 4 + 2) * 64 + tc * 4];
        float4 w3 = *(const float4*)&Ws[(k4 * 4 + 3) * 64 + tc * 4];
        fma4(acc0, x0.x, w0); fma4(acc0, x0.y, w1); fma4(acc0, x0.z, w2); fma4(acc0, x0.w, w3);
        fma4(acc1, x1.x, w0); fma4(acc1, x1.y, w1); fma4(acc1, x1.z, w2); fma4(acc1, x1.w, w3);
        fma4(acc2, x2.x, w0); fma4(acc2, x2.y, w1); fma4(acc2, x2.z, w2); fma4(acc2, x2.w, w3);
        fma4(acc3, x3.x, w0); fma4(acc3, x3.y, w1); fma4(acc3, x3.z, w2); fma4(acc3, x3.w, w3);
    }

    float4 asv = *(const float4*)&a_src[tc * 4];
    float4 adv = *(const float4*)&a_dst[tc * 4];
    float4 accs[4] = {acc0, acc1, acc2, acc3};
    #pragma unroll
    for (int i = 0; i < 4; ++i) {
        int row = n0 + tr * 4 + i;
        if (row < N) {
            float4 a = accs[i];
            float s1 = a.x * asv.x + a.y * asv.y + a.z * asv.z + a.w * asv.w;
            float s2 = a.x * adv.x + a.y * adv.y + a.z * adv.z + a.w * adv.w;
            #pragma unroll
            for (int o = 1; o < 16; o <<= 1) {
                s1 += __shfl_xor(s1, o, 64);
                s2 += __shfl_xor(s2, o, 64);
            }
            union { __half2 h2[2]; uint2 u; } pk;
            pk.h2[0] = __floats2half2_rn(a.x, a.y);
            pk.h2[1] = __floats2half2_rn(a.z, a.w);
            *(uint2*)&H[(size_t)row * 64 + tc * 4] = pk.u;
            if (tc == 0) { AS[row] = s1; AD[row] = s2; }
        }
    }
}

// ---------------- per-dst aggregation, lane-parallel softmax ----------------
template<int RELU, int NORM>
__global__ __launch_bounds__(256) void k_agg(
    const int* __restrict__ esrc, const int* __restrict__ offs,
    const __half* __restrict__ H, const float* __restrict__ AS,
    const float* __restrict__ AD, const float* __restrict__ bias,
    float* __restrict__ out, int N)
{
    __shared__ int2 sm[4][64];
    int gid = blockIdx.x * blockDim.x + threadIdx.x;
    int w = gid >> 6;
    int lane = gid & 63;
    int wid = threadIdx.x >> 6;
    if (w >= N) return;
    int beg = offs[w], end = offs[w + 1];
    int deg = end - beg;
    float bl = bias[lane];
    float val;
    if (deg == 0) {
        val = bl;
    } else if (deg <= 64) {
        float add = AD[w];
        int s = 0;
        float logit = -3.0e38f;
        if (lane < deg) {
            s = esrc[beg + lane];
            float l0 = AS[s] + add;
            logit = (l0 > 0.f) ? l0 : 0.2f * l0;
        }
        float m = logit;
        #pragma unroll
        for (int o = 32; o > 0; o >>= 1) m = fmaxf(m, __shfl_xor(m, o, 64));
        float wg = (lane < deg) ? __expf(logit - m) : 0.f;
        float z = wg;
        #pragma unroll
        for (int o = 32; o > 0; o >>= 1) z += __shfl_xor(z, o, 64);
        sm[wid][lane] = make_int2(s, __float_as_int(wg));
        float acc0 = 0.f, acc1 = 0.f;
        const __half* Hl = H + lane;
        int k = 0;
        #pragma unroll 2
        for (; k + 1 < deg; k += 2) {
            int4 v = *(const int4*)&sm[wid][k];   // two (src, weight) pairs
            acc0 = fmaf(__int_as_float(v.y), __half2float(Hl[(size_t)v.x * 64]), acc0);
            acc1 = fmaf(__int_as_float(v.w), __half2float(Hl[(size_t)v.z * 64]), acc1);
        }
        if (k < deg) {
            int2 v = sm[wid][k];
            acc0 = fmaf(__int_as_float(v.y), __half2float(Hl[(size_t)v.x * 64]), acc0);
        }
        val = (acc0 + acc1) / z + bl;
    } else {
        float add = AD[w];
        float m = -3.0e38f, z = 0.f, acc = 0.f;
        for (int i = beg; i < end; ++i) {
            int s = esrc[i];
            float l0 = AS[s] + add;
            l0 = (l0 > 0.f) ? l0 : 0.2f * l0;
            float mn = fmaxf(m, l0);
            float sc = __expf(m - mn);
            float wgt = __expf(l0 - mn);
            z = z * sc + wgt;
            acc = acc * sc + wgt * __half2float(H[(size_t)s * 64 + lane]);
            m = mn;
        }
        val = acc / z + bl;
    }
    if (RELU) val = fmaxf(val, 0.f);
    if (NORM) {
        float ss = val * val;
        #pragma unroll
        for (int o = 32; o > 0; o >>= 1) ss += __shfl_xor(ss, o, 64);
        val = val / fmaxf(sqrtf(ss), 1e-12f);
    }
    out[(size_t)w * 64 + lane] = val;
}

// ---------------- launch ----------------

extern "C" void kernel_launch(void* const* d_in, const int* in_sizes, int n_in,
                              void* d_out, int out_size, void* d_ws, size_t ws_size,
                              hipStream_t stream) {
    const float* x   = (const float*)d_in[0];
    const int*   ei  = (const int*)d_in[1];
    const float* W1  = (const float*)d_in[2];
    const float* as1 = (const float*)d_in[3];
    const float* ad1 = (const float*)d_in[4];
    const float* b1  = (const float*)d_in[5];
    const float* W2  = (const float*)d_in[6];
    const float* as2 = (const float*)d_in[7];
    const float* ad2 = (const float*)d_in[8];
    const float* b2  = (const float*)d_in[9];
    const int* src = ei;
    const int* dst = ei + NEDGES;

    char* ws = (char*)d_ws;
    size_t off = 0;
    auto alloc = [&](size_t bytes) -> void* {
        void* p = ws + off;
        off = (off + bytes + 255) & ~(size_t)255;
        return p;
    };
    __half* H    = (__half*)alloc((size_t)NNODES * 64 * 2);
    float* OUT1  = (float*)alloc((size_t)NNODES * 64 * 4);
    float* AS    = (float*)alloc((size_t)NNODES * 4);
    float* AD    = (float*)alloc((size_t)NNODES * 4);
    int*   offs  = (int*)alloc((size_t)(NNODES + 1) * 4);
    int2*  ep    = (int2*)alloc((size_t)NEDGES * 8);
    int*   esrc  = (int*)alloc((size_t)NEDGES * 4);
    int*   bcnt  = (int*)alloc((size_t)SCANL * 4);
    int*   boffs = (int*)alloc((size_t)SCANL * 4);
    int*   part1 = (int*)alloc((size_t)SCANB * 4);

    // CSR build (dst identical for both layers) — no global atomics
    k_bcount<<<NBLK1, 256, 0, stream>>>(dst, bcnt);
    k_scan_block<<<SCANB, 1024, 0, stream>>>(bcnt, boffs, part1, SCANL);
    k_scan_partial<<<1, 64, 0, stream>>>(part1, SCANB);
    k_bscatter<<<NBLK1, 256, 0, stream>>>(src, dst, boffs, part1, ep);
    k_fine<<<NBUCK, 256, 0, stream>>>(ep, boffs, part1, offs, esrc);

    // Layer 1
    k_gemm_att<128><<<(NNODES + 63) / 64, 256, 0, stream>>>(x, W1, as1, ad1, H, AS, AD, NNODES);
    k_agg<1, 0><<<((NNODES * 64) + 255) / 256, 256, 0, stream>>>(esrc, offs, H, AS, AD, b1, OUT1, NNODES);

    // Layer 2
    k_gemm_att<64><<<(NNODES + 63) / 64, 256, 0, stream>>>(OUT1, W2, as2, ad2, H, AS, AD, NNODES);
    k_agg<0, 1><<<((NNODES * 64) + 255) / 256, 256, 0, stream>>>(esrc, offs, H, AS, AD, b2, (float*)d_out, NNODES);
}

// Round 7
// 134.272 us; speedup vs baseline: 2.6928x; 1.0274x over previous
//
#include <hip/hip_runtime.h>
#include <hip/hip_fp16.h>
#include <math.h>

#define NNODES 50000
#define NEDGES 800000
#define NBUCK 256
#define EPB 4096
#define NBLK1 ((NEDGES + EPB - 1) / EPB)      // 196
#define SCANL (NBUCK * NBLK1)                  // 50176
#define SCANB ((SCANL + 1023) / 1024)          // 49

// ---------------- CSR build: two-level bucket sort, LDS atomics only ----------------

__global__ __launch_bounds__(256) void k_bcount(const int* __restrict__ dst,
                                                int* __restrict__ bcnt) {
    __shared__ int h[NBUCK];
    int t = threadIdx.x, b = blockIdx.x;
    h[t] = 0;
    __syncthreads();
    int beg = b * EPB, end = min(beg + EPB, NEDGES);
    for (int e = beg + t; e < end; e += 256) atomicAdd(&h[dst[e] >> 8], 1);
    __syncthreads();
    bcnt[t * NBLK1 + b] = h[t];
}

// hierarchical exclusive scan, level 1 (1024/block); partial[] holds block totals
__global__ void k_scan_block(const int* __restrict__ in, int* __restrict__ out,
                             int* __restrict__ partial, int n) {
    __shared__ int tmp[1024];
    int t = threadIdx.x;
    int i = blockIdx.x * 1024 + t;
    int v = (i < n) ? in[i] : 0;
    tmp[t] = v;
    __syncthreads();
    for (int off = 1; off < 1024; off <<= 1) {
        int u = (t >= off) ? tmp[t - off] : 0;
        __syncthreads();
        tmp[t] += u;
        __syncthreads();
    }
    if (i < n) out[i] = tmp[t] - v;
    if (t == 1023) partial[blockIdx.x] = tmp[t];
}

// in-block redundant exclusive scan of the <=64 level-2 partials
__device__ __forceinline__ void scan_partials(const int* __restrict__ partial, int* sp) {
    int t = threadIdx.x;
    if (t < 64) {
        int v = (t < SCANB) ? partial[t] : 0;
        int incl = v;
        #pragma unroll
        for (int off = 1; off < 64; off <<= 1) {
            int u = __shfl_up(incl, off, 64);
            if (t >= off) incl += u;
        }
        if (t < SCANB) sp[t] = incl - v;
    }
    __syncthreads();
}

// bucket scatter; LDS cursors seeded from scanned offsets
__global__ __launch_bounds__(256) void k_bscatter(const int* __restrict__ src,
                                                  const int* __restrict__ dst,
                                                  const int* __restrict__ boffs,
                                                  const int* __restrict__ partial,
                                                  int2* __restrict__ ep) {
    __shared__ int cur[NBUCK];
    __shared__ int sp[SCANB];
    int t = threadIdx.x, b = blockIdx.x;
    scan_partials(partial, sp);
    int idx = t * NBLK1 + b;
    cur[t] = boffs[idx] + sp[idx >> 10];
    __syncthreads();
    int beg = b * EPB, end = min(beg + EPB, NEDGES);
    for (int e = beg + t; e < end; e += 256) {
        int d = dst[e];
        int pos = atomicAdd(&cur[d >> 8], 1);
        ep[pos] = make_int2(d, src[e]);
    }
}

// per-bucket fine CSR: LDS histogram + LDS scan -> offs[] and dst-sorted esrc[]
__global__ __launch_bounds__(512) void k_fine(const int2* __restrict__ ep,
                                              const int* __restrict__ boffs,
                                              const int* __restrict__ partial,
                                              int* __restrict__ offs,
                                              int* __restrict__ esrc) {
    __shared__ int h[NBUCK];
    __shared__ int cur[NBUCK];
    __shared__ int sp[SCANB];
    int t = threadIdx.x, buck = blockIdx.x;
    scan_partials(partial, sp);
    int bi = buck * NBLK1;
    int base = boffs[bi] + sp[bi >> 10];
    int endp;
    if (buck == NBUCK - 1) endp = NEDGES;
    else {
        int ei2 = (buck + 1) * NBLK1;
        endp = boffs[ei2] + sp[ei2 >> 10];
    }
    if (t < NBUCK) h[t] = 0;
    __syncthreads();
    for (int i = base + t; i < endp; i += 512) atomicAdd(&h[ep[i].x & 255], 1);
    __syncthreads();
    int v = (t < NBUCK) ? h[t] : 0;
    for (int off = 1; off < 256; off <<= 1) {
        int u = (t >= off && t < NBUCK) ? h[t - off] : 0;
        __syncthreads();
        if (t < NBUCK) h[t] += u;
        __syncthreads();
    }
    if (t < NBUCK) {
        int excl = h[t] - v;
        int node = buck * 256 + t;
        if (node <= NNODES) offs[node] = base + excl;
        cur[t] = base + excl;
    }
    __syncthreads();
    for (int i = base + t; i < endp; i += 512) {
        int2 p = ep[i];
        int pos = atomicAdd(&cur[p.x & 255], 1);
        esrc[pos] = p.y;
    }
}

// ---------------- tiled SGEMM + attention-logit epilogue (fp16 H out) ----------------

__device__ __forceinline__ void fma4(float4& a, float s, const float4& w) {
    a.x = fmaf(s, w.x, a.x);
    a.y = fmaf(s, w.y, a.y);
    a.z = fmaf(s, w.z, a.z);
    a.w = fmaf(s, w.w, a.w);
}

template<int K>
__global__ __launch_bounds__(256, 2) void k_gemm_att(
    const float* __restrict__ X, const float* __restrict__ W,
    const float* __restrict__ a_src, const float* __restrict__ a_dst,
    __half* __restrict__ H, float* __restrict__ AS, float* __restrict__ AD, int N)
{
    constexpr int KF = K / 4;
    constexpr int KFS = (K == 128) ? 5 : 4;
    __shared__ float Xs[64 * K];
    __shared__ float Ws[K * 64];
    int t = threadIdx.x;
    int n0 = blockIdx.x * 64;

    const float4* W4 = (const float4*)W;
    #pragma unroll
    for (int f = t; f < K * 16; f += 256)
        ((float4*)Ws)[f] = W4[f];
    const float4* X4 = (const float4*)X;
    #pragma unroll
    for (int f = t; f < 64 * KF; f += 256) {
        int r = f >> KFS, k4 = f & (KF - 1);
        float4 v = {0.f, 0.f, 0.f, 0.f};
        if (n0 + r < N) v = X4[(size_t)(n0 + r) * KF + k4];
        ((float4*)&Xs[r * K])[k4 ^ ((r >> 2) & 3)] = v;
    }
    __syncthreads();

    int tr = t >> 4, tc = t & 15;
    int xi = tr & 3;
    const float4* xr0 = (const float4*)&Xs[(tr * 4 + 0) * K];
    const float4* xr1 = (const float4*)&Xs[(tr * 4 + 1) * K];
    const float4* xr2 = (const float4*)&Xs[(tr * 4 + 2) * K];
    const float4* xr3 = (const float4*)&Xs[(tr * 4 + 3) * K];
    float4 acc0 = {}, acc1 = {}, acc2 = {}, acc3 = {};

    #pragma unroll 2
    for (int k4 = 0; k4 < KF; ++k4) {
        int sl = k4 ^ xi;
        float4 x0 = xr0[sl], x1 = xr1[sl], x2 = xr2[sl], x3 = xr3[sl];
        float4 w0 = *(const float4*)&Ws[(k4 * 4 + 0) * 64 + tc * 4];
        float4 w1 = *(const float4*)&Ws[(k4 * 4 + 1) * 64 + tc * 4];
        float4 w2 = *(const float4*)&Ws[(k4 * 4 + 2) * 64 + tc * 4];
        float4 w3 = *(const float4*)&Ws[(k4 * 4 + 3) * 64 + tc * 4];
        fma4(acc0, x0.x, w0); fma4(acc0, x0.y, w1); fma4(acc0, x0.z, w2); fma4(acc0, x0.w, w3);
        fma4(acc1, x1.x, w0); fma4(acc1, x1.y, w1); fma4(acc1, x1.z, w2); fma4(acc1, x1.w, w3);
        fma4(acc2, x2.x, w0); fma4(acc2, x2.y, w1); fma4(acc2, x2.z, w2); fma4(acc2, x2.w, w3);
        fma4(acc3, x3.x, w0); fma4(acc3, x3.y, w1); fma4(acc3, x3.z, w2); fma4(acc3, x3.w, w3);
    }

    float4 asv = *(const float4*)&a_src[tc * 4];
    float4 adv = *(const float4*)&a_dst[tc * 4];
    float4 accs[4] = {acc0, acc1, acc2, acc3};
    #pragma unroll
    for (int i = 0; i < 4; ++i) {
        int row = n0 + tr * 4 + i;
        if (row < N) {
            float4 a = accs[i];
            float s1 = a.x * asv.x + a.y * asv.y + a.z * asv.z + a.w * asv.w;
            float s2 = a.x * adv.x + a.y * adv.y + a.z * adv.z + a.w * adv.w;
            #pragma unroll
            for (int o = 1; o < 16; o <<= 1) {
                s1 += __shfl_xor(s1, o, 64);
                s2 += __shfl_xor(s2, o, 64);
            }
            union { __half2 h2[2]; uint2 u; } pk;
            pk.h2[0] = __floats2half2_rn(a.x, a.y);
            pk.h2[1] = __floats2half2_rn(a.z, a.w);
            *(uint2*)&H[(size_t)row * 64 + tc * 4] = pk.u;
            if (tc == 0) { AS[row] = s1; AD[row] = s2; }
        }
    }
}

// ---------------- per-dst aggregation, lane-parallel softmax ----------------
// deg<=64 path: split-wave gather — lanes 0-31 even edges / 32-63 odd edges,
// each lane covers a feature PAIR via __half2 (duplicated across halves after combine).
template<int RELU, int NORM>
__global__ __launch_bounds__(256) void k_agg(
    const int* __restrict__ esrc, const int* __restrict__ offs,
    const __half* __restrict__ H, const float* __restrict__ AS,
    const float* __restrict__ AD, const float* __restrict__ bias,
    float* __restrict__ out, int N)
{
    __shared__ int2 sm[4][64];
    int gid = blockIdx.x * blockDim.x + threadIdx.x;
    int w = gid >> 6;
    int lane = gid & 63;
    int wid = threadIdx.x >> 6;
    if (w >= N) return;
    int beg = offs[w], end = offs[w + 1];
    int deg = end - beg;

    if (deg > 64) {  // rare fallback, lane = feature (wave-uniform branch)
        float bl = bias[lane];
        float add = AD[w];
        float m = -3.0e38f, z = 0.f, acc = 0.f;
        for (int i = beg; i < end; ++i) {
            int s = esrc[i];
            float l0 = AS[s] + add;
            l0 = (l0 > 0.f) ? l0 : 0.2f * l0;
            float mn = fmaxf(m, l0);
            float sc = __expf(m - mn);
            float wgt = __expf(l0 - mn);
            z = z * sc + wgt;
            acc = acc * sc + wgt * __half2float(H[(size_t)s * 64 + lane]);
            m = mn;
        }
        float val = acc / z + bl;
        if (RELU) val = fmaxf(val, 0.f);
        if (NORM) {
            float ss = val * val;
            #pragma unroll
            for (int o = 32; o > 0; o >>= 1) ss += __shfl_xor(ss, o, 64);
            val = val / fmaxf(sqrtf(ss), 1e-12f);
        }
        out[(size_t)w * 64 + lane] = val;
        return;
    }

    int half = lane >> 5, fp = lane & 31;
    float2 bp = ((const float2*)bias)[fp];
    float2 val2;
    if (deg == 0) {
        val2 = bp;
    } else {
        float add = AD[w];
        int s = 0;
        float logit = -3.0e38f;
        if (lane < deg) {
            s = esrc[beg + lane];                 // coalesced
            float l0 = AS[s] + add;               // cache-hot 4B gather
            logit = (l0 > 0.f) ? l0 : 0.2f * l0;  // leaky_relu
        }
        float m = logit;
        #pragma unroll
        for (int o = 32; o > 0; o >>= 1) m = fmaxf(m, __shfl_xor(m, o, 64));
        float wg = (lane < deg) ? __expf(logit - m) : 0.f;
        float z = wg;
        #pragma unroll
        for (int o = 32; o > 0; o >>= 1) z += __shfl_xor(z, o, 64);
        sm[wid][lane] = make_int2(s, __float_as_int(wg));

        const __half2* H2 = (const __half2*)H;
        float2 a0 = {0.f, 0.f}, a1 = {0.f, 0.f};
        int k = half;
        for (; k + 2 < deg; k += 4) {
            int2 v0 = sm[wid][k];
            int2 v1 = sm[wid][k + 2];
            float2 h0 = __half22float2(H2[(size_t)v0.x * 32 + fp]);
            float2 h1 = __half22float2(H2[(size_t)v1.x * 32 + fp]);
            float w0 = __int_as_float(v0.y), w1 = __int_as_float(v1.y);
            a0.x = fmaf(w0, h0.x, a0.x); a0.y = fmaf(w0, h0.y, a0.y);
            a1.x = fmaf(w1, h1.x, a1.x); a1.y = fmaf(w1, h1.y, a1.y);
        }
        if (k < deg) {
            int2 v0 = sm[wid][k];
            float2 h0 = __half22float2(H2[(size_t)v0.x * 32 + fp]);
            float w0 = __int_as_float(v0.y);
            a0.x = fmaf(w0, h0.x, a0.x); a0.y = fmaf(w0, h0.y, a0.y);
        }
        float2 acc = {a0.x + a1.x, a0.y + a1.y};
        acc.x += __shfl_xor(acc.x, 32, 64);   // combine even/odd edge halves
        acc.y += __shfl_xor(acc.y, 32, 64);
        float rz = 1.0f / z;
        val2 = make_float2(fmaf(acc.x, rz, bp.x), fmaf(acc.y, rz, bp.y));
    }
    if (RELU) { val2.x = fmaxf(val2.x, 0.f); val2.y = fmaxf(val2.y, 0.f); }
    if (NORM) {
        float ss = val2.x * val2.x + val2.y * val2.y;
        #pragma unroll
        for (int o = 16; o > 0; o >>= 1) ss += __shfl_xor(ss, o, 64);  // within 32-lane half
        float inv = 1.0f / fmaxf(sqrtf(ss), 1e-12f);
        val2.x *= inv; val2.y *= inv;
    }
    if (half == 0) ((float2*)out)[(size_t)w * 32 + fp] = val2;
}

// ---------------- launch ----------------

extern "C" void kernel_launch(void* const* d_in, const int* in_sizes, int n_in,
                              void* d_out, int out_size, void* d_ws, size_t ws_size,
                              hipStream_t stream) {
    const float* x   = (const float*)d_in[0];
    const int*   ei  = (const int*)d_in[1];
    const float* W1  = (const float*)d_in[2];
    const float* as1 = (const float*)d_in[3];
    const float* ad1 = (const float*)d_in[4];
    const float* b1  = (const float*)d_in[5];
    const float* W2  = (const float*)d_in[6];
    const float* as2 = (const float*)d_in[7];
    const float* ad2 = (const float*)d_in[8];
    const float* b2  = (const float*)d_in[9];
    const int* src = ei;
    const int* dst = ei + NEDGES;

    char* ws = (char*)d_ws;
    size_t off = 0;
    auto alloc = [&](size_t bytes) -> void* {
        void* p = ws + off;
        off = (off + bytes + 255) & ~(size_t)255;
        return p;
    };
    __half* H    = (__half*)alloc((size_t)NNODES * 64 * 2);
    float* OUT1  = (float*)alloc((size_t)NNODES * 64 * 4);
    float* AS    = (float*)alloc((size_t)NNODES * 4);
    float* AD    = (float*)alloc((size_t)NNODES * 4);
    int*   offs  = (int*)alloc((size_t)(NNODES + 1) * 4);
    int2*  ep    = (int2*)alloc((size_t)NEDGES * 8);
    int*   esrc  = (int*)alloc((size_t)NEDGES * 4);
    int*   bcnt  = (int*)alloc((size_t)SCANL * 4);
    int*   boffs = (int*)alloc((size_t)SCANL * 4);
    int*   part1 = (int*)alloc((size_t)SCANB * 4);

    // CSR build (dst identical for both layers) — no global atomics
    k_bcount<<<NBLK1, 256, 0, stream>>>(dst, bcnt);
    k_scan_block<<<SCANB, 1024, 0, stream>>>(bcnt, boffs, part1, SCANL);
    k_bscatter<<<NBLK1, 256, 0, stream>>>(src, dst, boffs, part1, ep);
    k_fine<<<NBUCK, 512, 0, stream>>>(ep, boffs, part1, offs, esrc);

    // Layer 1
    k_gemm_att<128><<<(NNODES + 63) / 64, 256, 0, stream>>>(x, W1, as1, ad1, H, AS, AD, NNODES);
    k_agg<1, 0><<<((NNODES * 64) + 255) / 256, 256, 0, stream>>>(esrc, offs, H, AS, AD, b1, OUT1, NNODES);

    // Layer 2
    k_gemm_att<64><<<(NNODES + 63) / 64, 256, 0, stream>>>(OUT1, W2, as2, ad2, H, AS, AD, NNODES);
    k_agg<0, 1><<<((NNODES * 64) + 255) / 256, 256, 0, stream>>>(esrc, offs, H, AS, AD, b2, (float*)d_out, NNODES);
}

// Round 8
// 120.877 us; speedup vs baseline: 2.9912x; 1.1108x over previous
//
#include <hip/hip_runtime.h>
#include <hip/hip_fp16.h>
#include <math.h>

#define NNODES 50000
#define NEDGES 800000
#define NBUCK 256
#define EPB 4096
#define NBLK1 ((NEDGES + EPB - 1) / EPB)      // 196
#define SCANL (NBUCK * NBLK1)                  // 50176
#define SCANB ((SCANL + 1023) / 1024)          // 49

// ---------------- CSR build: two-level bucket sort, LDS atomics only ----------------

__global__ __launch_bounds__(256) void k_bcount(const int* __restrict__ dst,
                                                int* __restrict__ bcnt) {
    __shared__ int h[NBUCK];
    int t = threadIdx.x, b = blockIdx.x;
    h[t] = 0;
    __syncthreads();
    int beg = b * EPB, end = min(beg + EPB, NEDGES);
    for (int e = beg + t; e < end; e += 256) atomicAdd(&h[dst[e] >> 8], 1);
    __syncthreads();
    bcnt[t * NBLK1 + b] = h[t];
}

__global__ void k_scan_block(const int* __restrict__ in, int* __restrict__ out,
                             int* __restrict__ partial, int n) {
    __shared__ int tmp[1024];
    int t = threadIdx.x;
    int i = blockIdx.x * 1024 + t;
    int v = (i < n) ? in[i] : 0;
    tmp[t] = v;
    __syncthreads();
    for (int off = 1; off < 1024; off <<= 1) {
        int u = (t >= off) ? tmp[t - off] : 0;
        __syncthreads();
        tmp[t] += u;
        __syncthreads();
    }
    if (i < n) out[i] = tmp[t] - v;
    if (t == 1023) partial[blockIdx.x] = tmp[t];
}

__device__ __forceinline__ void scan_partials(const int* __restrict__ partial, int* sp) {
    int t = threadIdx.x;
    if (t < 64) {
        int v = (t < SCANB) ? partial[t] : 0;
        int incl = v;
        #pragma unroll
        for (int off = 1; off < 64; off <<= 1) {
            int u = __shfl_up(incl, off, 64);
            if (t >= off) incl += u;
        }
        if (t < SCANB) sp[t] = incl - v;
    }
    __syncthreads();
}

__global__ __launch_bounds__(256) void k_bscatter(const int* __restrict__ src,
                                                  const int* __restrict__ dst,
                                                  const int* __restrict__ boffs,
                                                  const int* __restrict__ partial,
                                                  int2* __restrict__ ep) {
    __shared__ int cur[NBUCK];
    __shared__ int sp[SCANB];
    int t = threadIdx.x, b = blockIdx.x;
    scan_partials(partial, sp);
    int idx = t * NBLK1 + b;
    cur[t] = boffs[idx] + sp[idx >> 10];
    __syncthreads();
    int beg = b * EPB, end = min(beg + EPB, NEDGES);
    for (int e = beg + t; e < end; e += 256) {
        int d = dst[e];
        int pos = atomicAdd(&cur[d >> 8], 1);
        ep[pos] = make_int2(d, src[e]);
    }
}

__global__ __launch_bounds__(512) void k_fine(const int2* __restrict__ ep,
                                              const int* __restrict__ boffs,
                                              const int* __restrict__ partial,
                                              int* __restrict__ offs,
                                              int* __restrict__ esrc) {
    __shared__ int h[NBUCK];
    __shared__ int cur[NBUCK];
    __shared__ int sp[SCANB];
    int t = threadIdx.x, buck = blockIdx.x;
    scan_partials(partial, sp);
    int bi = buck * NBLK1;
    int base = boffs[bi] + sp[bi >> 10];
    int endp;
    if (buck == NBUCK - 1) endp = NEDGES;
    else {
        int ei2 = (buck + 1) * NBLK1;
        endp = boffs[ei2] + sp[ei2 >> 10];
    }
    if (t < NBUCK) h[t] = 0;
    __syncthreads();
    for (int i = base + t; i < endp; i += 512) atomicAdd(&h[ep[i].x & 255], 1);
    __syncthreads();
    int v = (t < NBUCK) ? h[t] : 0;
    for (int off = 1; off < 256; off <<= 1) {
        int u = (t >= off && t < NBUCK) ? h[t - off] : 0;
        __syncthreads();
        if (t < NBUCK) h[t] += u;
        __syncthreads();
    }
    if (t < NBUCK) {
        int excl = h[t] - v;
        int node = buck * 256 + t;
        if (node <= NNODES) offs[node] = base + excl;
        cur[t] = base + excl;
    }
    __syncthreads();
    for (int i = base + t; i < endp; i += 512) {
        int2 p = ep[i];
        int pos = atomicAdd(&cur[p.x & 255], 1);
        esrc[pos] = p.y;
    }
}

// ---------------- tiled SGEMM + attention-logit epilogue (fp16 H out) ----------------

__device__ __forceinline__ void fma4(float4& a, float s, const float4& w) {
    a.x = fmaf(s, w.x, a.x);
    a.y = fmaf(s, w.y, a.y);
    a.z = fmaf(s, w.z, a.z);
    a.w = fmaf(s, w.w, a.w);
}

// XH: X is __half (64 wide); else float.
template<int K, int XH>
__global__ __launch_bounds__(256, 2) void k_gemm_att(
    const void* __restrict__ Xv, const float* __restrict__ W,
    const float* __restrict__ a_src, const float* __restrict__ a_dst,
    __half* __restrict__ H, float* __restrict__ AS, float* __restrict__ AD, int N)
{
    constexpr int KF = K / 4;
    constexpr int KFS = (K == 128) ? 5 : 4;
    __shared__ float Xs[64 * K];
    __shared__ float Ws[K * 64];
    int t = threadIdx.x;
    int n0 = blockIdx.x * 64;

    const float4* W4 = (const float4*)W;
    #pragma unroll
    for (int f = t; f < K * 16; f += 256)
        ((float4*)Ws)[f] = W4[f];
    #pragma unroll
    for (int f = t; f < 64 * KF; f += 256) {
        int r = f >> KFS, k4 = f & (KF - 1);
        float4 v = {0.f, 0.f, 0.f, 0.f};
        if (n0 + r < N) {
            if (XH) {
                union { uint2 u; __half2 h2[2]; } c;
                c.u = ((const uint2*)Xv)[(size_t)(n0 + r) * KF + k4];
                float2 lo = __half22float2(c.h2[0]);
                float2 hi = __half22float2(c.h2[1]);
                v = make_float4(lo.x, lo.y, hi.x, hi.y);
            } else {
                v = ((const float4*)Xv)[(size_t)(n0 + r) * KF + k4];
            }
        }
        ((float4*)&Xs[r * K])[k4 ^ ((r >> 2) & 3)] = v;
    }
    __syncthreads();

    int tr = t >> 4, tc = t & 15;
    int xi = tr & 3;
    const float4* xr0 = (const float4*)&Xs[(tr * 4 + 0) * K];
    const float4* xr1 = (const float4*)&Xs[(tr * 4 + 1) * K];
    const float4* xr2 = (const float4*)&Xs[(tr * 4 + 2) * K];
    const float4* xr3 = (const float4*)&Xs[(tr * 4 + 3) * K];
    float4 acc0 = {}, acc1 = {}, acc2 = {}, acc3 = {};

    #pragma unroll 2
    for (int k4 = 0; k4 < KF; ++k4) {
        int sl = k4 ^ xi;
        float4 x0 = xr0[sl], x1 = xr1[sl], x2 = xr2[sl], x3 = xr3[sl];
        float4 w0 = *(const float4*)&Ws[(k4 * 4 + 0) * 64 + tc * 4];
        float4 w1 = *(const float4*)&Ws[(k4 * 4 + 1) * 64 + tc * 4];
        float4 w2 = *(const float4*)&Ws[(k4 * 4 + 2) * 64 + tc * 4];
        float4 w3 = *(const float4*)&Ws[(k4 * 4 + 3) * 64 + tc * 4];
        fma4(acc0, x0.x, w0); fma4(acc0, x0.y, w1); fma4(acc0, x0.z, w2); fma4(acc0, x0.w, w3);
        fma4(acc1, x1.x, w0); fma4(acc1, x1.y, w1); fma4(acc1, x1.z, w2); fma4(acc1, x1.w, w3);
        fma4(acc2, x2.x, w0); fma4(acc2, x2.y, w1); fma4(acc2, x2.z, w2); fma4(acc2, x2.w, w3);
        fma4(acc3, x3.x, w0); fma4(acc3, x3.y, w1); fma4(acc3, x3.z, w2); fma4(acc3, x3.w, w3);
    }

    float4 asv = *(const float4*)&a_src[tc * 4];
    float4 adv = *(const float4*)&a_dst[tc * 4];
    float4 accs[4] = {acc0, acc1, acc2, acc3};
    #pragma unroll
    for (int i = 0; i < 4; ++i) {
        int row = n0 + tr * 4 + i;
        if (row < N) {
            float4 a = accs[i];
            float s1 = a.x * asv.x + a.y * asv.y + a.z * asv.z + a.w * asv.w;
            float s2 = a.x * adv.x + a.y * adv.y + a.z * adv.z + a.w * adv.w;
            #pragma unroll
            for (int o = 1; o < 16; o <<= 1) {
                s1 += __shfl_xor(s1, o, 64);
                s2 += __shfl_xor(s2, o, 64);
            }
            union { __half2 h2[2]; uint2 u; } pk;
            pk.h2[0] = __floats2half2_rn(a.x, a.y);
            pk.h2[1] = __floats2half2_rn(a.z, a.w);
            *(uint2*)&H[(size_t)row * 64 + tc * 4] = pk.u;
            if (tc == 0) { AS[row] = s1; AD[row] = s2; }
        }
    }
}

// ---------------- per-dst aggregation: 2 nodes per wave ----------------
// Fast path (both degs<=32): each 32-lane half owns one node; lane = feature-pair.
// Fallbacks: full-wave (deg<=64) and serial (deg>64) per node, rare.
template<int RELU, int NORM, int OUTH>
__global__ __launch_bounds__(256) void k_agg(
    const int* __restrict__ esrc, const int* __restrict__ offs,
    const __half* __restrict__ H, const float* __restrict__ AS,
    const float* __restrict__ AD, const float* __restrict__ bias,
    void* __restrict__ outv, int N)
{
    __shared__ int2 sm[4][64];
    int gid = blockIdx.x * blockDim.x + threadIdx.x;
    int w = gid >> 6;
    int lane = gid & 63;
    int wid = threadIdx.x >> 6;
    int n0 = 2 * w;
    if (n0 >= N) return;
    int half = lane >> 5, fp = lane & 31;
    int nh = n0 + half;
    bool valid = nh < N;
    int beg = valid ? offs[nh] : 0;
    int end = valid ? offs[nh + 1] : 0;
    int deg = end - beg;
    int degO = __shfl_xor(deg, 32, 64);
    int dm = max(deg, degO);
    float2 bp = ((const float2*)bias)[fp];

    if (dm <= 32) {
        float add = valid ? AD[nh] : 0.f;
        int s = 0;
        float logit = -3.0e38f;
        if (fp < deg) {
            s = esrc[beg + fp];
            float l0 = AS[s] + add;
            logit = (l0 > 0.f) ? l0 : 0.2f * l0;
        }
        float m = logit;
        #pragma unroll
        for (int o = 16; o > 0; o >>= 1) m = fmaxf(m, __shfl_xor(m, o, 64));
        float wg = (fp < deg) ? __expf(logit - m) : 0.f;
        float z = wg;
        #pragma unroll
        for (int o = 16; o > 0; o >>= 1) z += __shfl_xor(z, o, 64);
        sm[wid][lane] = make_int2(s, __float_as_int(wg));

        const __half2* H2 = (const __half2*)H;
        float2 a0 = {0.f, 0.f}, a1 = {0.f, 0.f};
        int base = half * 32;
        int k = 0;
        for (; k + 1 < dm; k += 2) {
            int4 v = *(const int4*)&sm[wid][base + k];
            float2 h0 = __half22float2(H2[(size_t)v.x * 32 + fp]);
            float2 h1 = __half22float2(H2[(size_t)v.z * 32 + fp]);
            float w0 = __int_as_float(v.y), w1 = __int_as_float(v.w);
            a0.x = fmaf(w0, h0.x, a0.x); a0.y = fmaf(w0, h0.y, a0.y);
            a1.x = fmaf(w1, h1.x, a1.x); a1.y = fmaf(w1, h1.y, a1.y);
        }
        if (k < dm) {
            int2 v = sm[wid][base + k];
            float2 h0 = __half22float2(H2[(size_t)v.x * 32 + fp]);
            float w0 = __int_as_float(v.y);
            a0.x = fmaf(w0, h0.x, a0.x); a0.y = fmaf(w0, h0.y, a0.y);
        }
        float2 acc = {a0.x + a1.x, a0.y + a1.y};
        float rz = (deg > 0) ? (1.0f / z) : 0.f;
        float2 val2 = make_float2(fmaf(acc.x, rz, bp.x), fmaf(acc.y, rz, bp.y));
        if (RELU) { val2.x = fmaxf(val2.x, 0.f); val2.y = fmaxf(val2.y, 0.f); }
        if (NORM) {
            float ss = val2.x * val2.x + val2.y * val2.y;
            #pragma unroll
            for (int o = 16; o > 0; o >>= 1) ss += __shfl_xor(ss, o, 64);
            float inv = 1.0f / fmaxf(sqrtf(ss), 1e-12f);
            val2.x *= inv; val2.y *= inv;
        }
        if (valid) {
            if (OUTH) ((__half2*)outv)[(size_t)nh * 32 + fp] = __floats2half2_rn(val2.x, val2.y);
            else      ((float2*)outv)[(size_t)nh * 32 + fp] = val2;
        }
        return;
    }

    // ---- rare fallback: per node with the full wave ----
    #pragma unroll 1
    for (int side = 0; side < 2; ++side) {
        int n = n0 + side;
        if (n >= N) break;
        int b2 = offs[n], e2 = offs[n + 1];
        int dg = e2 - b2;
        float add = AD[n];
        if (dg <= 64) {
            int s = 0;
            float logit = -3.0e38f;
            if (lane < dg) {
                s = esrc[b2 + lane];
                float l0 = AS[s] + add;
                logit = (l0 > 0.f) ? l0 : 0.2f * l0;
            }
            float m = logit;
            #pragma unroll
            for (int o = 32; o > 0; o >>= 1) m = fmaxf(m, __shfl_xor(m, o, 64));
            float wg = (lane < dg) ? __expf(logit - m) : 0.f;
            float z = wg;
            #pragma unroll
            for (int o = 32; o > 0; o >>= 1) z += __shfl_xor(z, o, 64);
            sm[wid][lane] = make_int2(s, __float_as_int(wg));
            const __half2* H2 = (const __half2*)H;
            float2 a0 = {0.f, 0.f};
            for (int k = half; k < dg; k += 2) {
                int2 v = sm[wid][k];
                float2 h0 = __half22float2(H2[(size_t)v.x * 32 + fp]);
                float w0 = __int_as_float(v.y);
                a0.x = fmaf(w0, h0.x, a0.x); a0.y = fmaf(w0, h0.y, a0.y);
            }
            a0.x += __shfl_xor(a0.x, 32, 64);
            a0.y += __shfl_xor(a0.y, 32, 64);
            float rz = (dg > 0) ? (1.0f / z) : 0.f;
            float2 val2 = make_float2(fmaf(a0.x, rz, bp.x), fmaf(a0.y, rz, bp.y));
            if (RELU) { val2.x = fmaxf(val2.x, 0.f); val2.y = fmaxf(val2.y, 0.f); }
            if (NORM) {
                float ss = val2.x * val2.x + val2.y * val2.y;
                #pragma unroll
                for (int o = 16; o > 0; o >>= 1) ss += __shfl_xor(ss, o, 64);
                float inv = 1.0f / fmaxf(sqrtf(ss), 1e-12f);
                val2.x *= inv; val2.y *= inv;
            }
            if (half == 0) {
                if (OUTH) ((__half2*)outv)[(size_t)n * 32 + fp] = __floats2half2_rn(val2.x, val2.y);
                else      ((float2*)outv)[(size_t)n * 32 + fp] = val2;
            }
        } else {
            float m = -3.0e38f, z = 0.f, acc = 0.f;
            for (int i = b2; i < e2; ++i) {
                int s = esrc[i];
                float l0 = AS[s] + add;
                l0 = (l0 > 0.f) ? l0 : 0.2f * l0;
                float mn = fmaxf(m, l0);
                float sc = __expf(m - mn);
                float wgt = __expf(l0 - mn);
                z = z * sc + wgt;
                acc = acc * sc + wgt * __half2float(H[(size_t)s * 64 + lane]);
                m = mn;
            }
            float val = acc / z + ((lane & 1) ? bp.y : bp.x);
            // bias: lane covers feature 'lane'; reload properly
            val = acc / z + bias[lane];
            if (RELU) val = fmaxf(val, 0.f);
            if (NORM) {
                float ss = val * val;
                #pragma unroll
                for (int o = 32; o > 0; o >>= 1) ss += __shfl_xor(ss, o, 64);
                val = val / fmaxf(sqrtf(ss), 1e-12f);
            }
            if (OUTH) ((__half*)outv)[(size_t)n * 64 + lane] = __float2half(val);
            else      ((float*)outv)[(size_t)n * 64 + lane] = val;
        }
    }
}

// ---------------- launch ----------------

extern "C" void kernel_launch(void* const* d_in, const int* in_sizes, int n_in,
                              void* d_out, int out_size, void* d_ws, size_t ws_size,
                              hipStream_t stream) {
    const float* x   = (const float*)d_in[0];
    const int*   ei  = (const int*)d_in[1];
    const float* W1  = (const float*)d_in[2];
    const float* as1 = (const float*)d_in[3];
    const float* ad1 = (const float*)d_in[4];
    const float* b1  = (const float*)d_in[5];
    const float* W2  = (const float*)d_in[6];
    const float* as2 = (const float*)d_in[7];
    const float* ad2 = (const float*)d_in[8];
    const float* b2  = (const float*)d_in[9];
    const int* src = ei;
    const int* dst = ei + NEDGES;

    char* ws = (char*)d_ws;
    size_t off = 0;
    auto alloc = [&](size_t bytes) -> void* {
        void* p = ws + off;
        off = (off + bytes + 255) & ~(size_t)255;
        return p;
    };
    __half* H    = (__half*)alloc((size_t)NNODES * 64 * 2);
    __half* OUT1 = (__half*)alloc((size_t)NNODES * 64 * 2);
    float* AS    = (float*)alloc((size_t)NNODES * 4);
    float* AD    = (float*)alloc((size_t)NNODES * 4);
    int*   offs  = (int*)alloc((size_t)(NNODES + 1) * 4);
    int2*  ep    = (int2*)alloc((size_t)NEDGES * 8);
    int*   esrc  = (int*)alloc((size_t)NEDGES * 4);
    int*   bcnt  = (int*)alloc((size_t)SCANL * 4);
    int*   boffs = (int*)alloc((size_t)SCANL * 4);
    int*   part1 = (int*)alloc((size_t)SCANB * 4);

    // CSR build (dst identical for both layers) — no global atomics
    k_bcount<<<NBLK1, 256, 0, stream>>>(dst, bcnt);
    k_scan_block<<<SCANB, 1024, 0, stream>>>(bcnt, boffs, part1, SCANL);
    k_bscatter<<<NBLK1, 256, 0, stream>>>(src, dst, boffs, part1, ep);
    k_fine<<<NBUCK, 512, 0, stream>>>(ep, boffs, part1, offs, esrc);

    int aggBlocks = (NNODES / 2 + 3) / 4;  // 2 nodes/wave, 4 waves/block
    // Layer 1
    k_gemm_att<128, 0><<<(NNODES + 63) / 64, 256, 0, stream>>>(x, W1, as1, ad1, H, AS, AD, NNODES);
    k_agg<1, 0, 1><<<aggBlocks, 256, 0, stream>>>(esrc, offs, H, AS, AD, b1, OUT1, NNODES);

    // Layer 2
    k_gemm_att<64, 1><<<(NNODES + 63) / 64, 256, 0, stream>>>(OUT1, W2, as2, ad2, H, AS, AD, NNODES);
    k_agg<0, 1, 0><<<aggBlocks, 256, 0, stream>>>(esrc, offs, H, AS, AD, b2, d_out, NNODES);
}

// Round 9
// 118.226 us; speedup vs baseline: 3.0583x; 1.0224x over previous
//
#include <hip/hip_runtime.h>
#include <hip/hip_fp16.h>
#include <math.h>

#define NNODES 50000
#define NEDGES 800000
#define NBUCK 256
#define EPB 4096
#define NBLK1 ((NEDGES + EPB - 1) / EPB)      // 196
#define SCANL (NBUCK * NBLK1)                  // 50176
#define SCANB ((SCANL + 1023) / 1024)          // 49
#define FCAP 8192                              // per-bucket LDS sort capacity

// ---------------- CSR build: two-level bucket sort, LDS atomics only ----------------
// Edge record packed into int32: (src << 8) | (dst & 255).  src < 2^17, so fits.

__global__ __launch_bounds__(256) void k_bcount(const int* __restrict__ dst,
                                                int* __restrict__ bcnt) {
    __shared__ int h[NBUCK];
    int t = threadIdx.x, b = blockIdx.x;
    h[t] = 0;
    __syncthreads();
    int beg = b * EPB, end = min(beg + EPB, NEDGES);
    for (int e = beg + t; e < end; e += 256) atomicAdd(&h[dst[e] >> 8], 1);
    __syncthreads();
    bcnt[t * NBLK1 + b] = h[t];
}

__global__ void k_scan_block(const int* __restrict__ in, int* __restrict__ out,
                             int* __restrict__ partial, int n) {
    __shared__ int tmp[1024];
    int t = threadIdx.x;
    int i = blockIdx.x * 1024 + t;
    int v = (i < n) ? in[i] : 0;
    tmp[t] = v;
    __syncthreads();
    for (int off = 1; off < 1024; off <<= 1) {
        int u = (t >= off) ? tmp[t - off] : 0;
        __syncthreads();
        tmp[t] += u;
        __syncthreads();
    }
    if (i < n) out[i] = tmp[t] - v;
    if (t == 1023) partial[blockIdx.x] = tmp[t];
}

__device__ __forceinline__ void scan_partials(const int* __restrict__ partial, int* sp) {
    int t = threadIdx.x;
    if (t < 64) {
        int v = (t < SCANB) ? partial[t] : 0;
        int incl = v;
        #pragma unroll
        for (int off = 1; off < 64; off <<= 1) {
            int u = __shfl_up(incl, off, 64);
            if (t >= off) incl += u;
        }
        if (t < SCANB) sp[t] = incl - v;
    }
    __syncthreads();
}

__global__ __launch_bounds__(256) void k_bscatter(const int* __restrict__ src,
                                                  const int* __restrict__ dst,
                                                  const int* __restrict__ boffs,
                                                  const int* __restrict__ partial,
                                                  int* __restrict__ ep) {
    __shared__ int cur[NBUCK];
    __shared__ int sp[SCANB];
    int t = threadIdx.x, b = blockIdx.x;
    scan_partials(partial, sp);
    int idx = t * NBLK1 + b;
    cur[t] = boffs[idx] + sp[idx >> 10];
    __syncthreads();
    int beg = b * EPB, end = min(beg + EPB, NEDGES);
    for (int e = beg + t; e < end; e += 256) {
        int d = dst[e];
        int pos = atomicAdd(&cur[d >> 8], 1);
        ep[pos] = (src[e] << 8) | (d & 255);
    }
}

// per-bucket fine CSR via in-LDS counting sort; coalesced esrc writes
__global__ __launch_bounds__(512) void k_fine(const int* __restrict__ ep,
                                              const int* __restrict__ boffs,
                                              const int* __restrict__ partial,
                                              int* __restrict__ offs,
                                              int* __restrict__ esrc) {
    __shared__ int h[NBUCK];
    __shared__ int cur[NBUCK];
    __shared__ int sp[SCANB];
    __shared__ int stg[FCAP];
    __shared__ int srt[FCAP];
    int t = threadIdx.x, buck = blockIdx.x;
    scan_partials(partial, sp);
    int bi = buck * NBLK1;
    int base = boffs[bi] + sp[bi >> 10];
    int endp;
    if (buck == NBUCK - 1) endp = NEDGES;
    else {
        int ei2 = (buck + 1) * NBLK1;
        endp = boffs[ei2] + sp[ei2 >> 10];
    }
    int cnt = endp - base;
    bool fits = (cnt <= FCAP);

    if (t < NBUCK) h[t] = 0;
    __syncthreads();
    if (fits) {
        for (int j = t; j < cnt; j += 512) stg[j] = ep[base + j];   // coalesced, once
        __syncthreads();
        for (int j = t; j < cnt; j += 512) atomicAdd(&h[stg[j] & 255], 1);
    } else {
        for (int i = base + t; i < endp; i += 512) atomicAdd(&h[ep[i] & 255], 1);
    }
    __syncthreads();
    int v = (t < NBUCK) ? h[t] : 0;
    for (int off = 1; off < 256; off <<= 1) {
        int u = (t >= off && t < NBUCK) ? h[t - off] : 0;
        __syncthreads();
        if (t < NBUCK) h[t] += u;
        __syncthreads();
    }
    if (t < NBUCK) {
        int excl = h[t] - v;
        int node = buck * 256 + t;
        if (node <= NNODES) offs[node] = base + excl;
        cur[t] = excl;                                   // local offsets
    }
    __syncthreads();
    if (fits) {
        for (int j = t; j < cnt; j += 512) {
            int p = stg[j];
            int pos = atomicAdd(&cur[p & 255], 1);
            srt[pos] = p >> 8;                           // LDS counting sort
        }
        __syncthreads();
        for (int j = t; j < cnt; j += 512) esrc[base + j] = srt[j];  // coalesced
    } else {
        for (int i = base + t; i < endp; i += 512) {
            int p = ep[i];
            int pos = atomicAdd(&cur[p & 255], 1);
            esrc[base + pos] = p >> 8;
        }
    }
}

// ---------------- tiled SGEMM + attention-logit epilogue (fp16 H out) ----------------

__device__ __forceinline__ void fma4(float4& a, float s, const float4& w) {
    a.x = fmaf(s, w.x, a.x);
    a.y = fmaf(s, w.y, a.y);
    a.z = fmaf(s, w.z, a.z);
    a.w = fmaf(s, w.w, a.w);
}

// XH: X is __half (64 wide); else float.
template<int K, int XH>
__global__ __launch_bounds__(256, 2) void k_gemm_att(
    const void* __restrict__ Xv, const float* __restrict__ W,
    const float* __restrict__ a_src, const float* __restrict__ a_dst,
    __half* __restrict__ H, float* __restrict__ AS, float* __restrict__ AD, int N)
{
    constexpr int KF = K / 4;
    constexpr int KFS = (K == 128) ? 5 : 4;
    __shared__ float Xs[64 * K];
    __shared__ float Ws[K * 64];
    int t = threadIdx.x;
    int n0 = blockIdx.x * 64;

    const float4* W4 = (const float4*)W;
    #pragma unroll
    for (int f = t; f < K * 16; f += 256)
        ((float4*)Ws)[f] = W4[f];
    #pragma unroll
    for (int f = t; f < 64 * KF; f += 256) {
        int r = f >> KFS, k4 = f & (KF - 1);
        float4 v = {0.f, 0.f, 0.f, 0.f};
        if (n0 + r < N) {
            if (XH) {
                union { uint2 u; __half2 h2[2]; } c;
                c.u = ((const uint2*)Xv)[(size_t)(n0 + r) * KF + k4];
                float2 lo = __half22float2(c.h2[0]);
                float2 hi = __half22float2(c.h2[1]);
                v = make_float4(lo.x, lo.y, hi.x, hi.y);
            } else {
                v = ((const float4*)Xv)[(size_t)(n0 + r) * KF + k4];
            }
        }
        ((float4*)&Xs[r * K])[k4 ^ ((r >> 2) & 3)] = v;
    }
    __syncthreads();

    int tr = t >> 4, tc = t & 15;
    int xi = tr & 3;
    const float4* xr0 = (const float4*)&Xs[(tr * 4 + 0) * K];
    const float4* xr1 = (const float4*)&Xs[(tr * 4 + 1) * K];
    const float4* xr2 = (const float4*)&Xs[(tr * 4 + 2) * K];
    const float4* xr3 = (const float4*)&Xs[(tr * 4 + 3) * K];
    float4 acc0 = {}, acc1 = {}, acc2 = {}, acc3 = {};

    #pragma unroll 2
    for (int k4 = 0; k4 < KF; ++k4) {
        int sl = k4 ^ xi;
        float4 x0 = xr0[sl], x1 = xr1[sl], x2 = xr2[sl], x3 = xr3[sl];
        float4 w0 = *(const float4*)&Ws[(k4 * 4 + 0) * 64 + tc * 4];
        float4 w1 = *(const float4*)&Ws[(k4 * 4 + 1) * 64 + tc * 4];
        float4 w2 = *(const float4*)&Ws[(k4 * 4 + 2) * 64 + tc * 4];
        float4 w3 = *(const float4*)&Ws[(k4 * 4 + 3) * 64 + tc * 4];
        fma4(acc0, x0.x, w0); fma4(acc0, x0.y, w1); fma4(acc0, x0.z, w2); fma4(acc0, x0.w, w3);
        fma4(acc1, x1.x, w0); fma4(acc1, x1.y, w1); fma4(acc1, x1.z, w2); fma4(acc1, x1.w, w3);
        fma4(acc2, x2.x, w0); fma4(acc2, x2.y, w1); fma4(acc2, x2.z, w2); fma4(acc2, x2.w, w3);
        fma4(acc3, x3.x, w0); fma4(acc3, x3.y, w1); fma4(acc3, x3.z, w2); fma4(acc3, x3.w, w3);
    }

    float4 asv = *(const float4*)&a_src[tc * 4];
    float4 adv = *(const float4*)&a_dst[tc * 4];
    float4 accs[4] = {acc0, acc1, acc2, acc3};
    #pragma unroll
    for (int i = 0; i < 4; ++i) {
        int row = n0 + tr * 4 + i;
        if (row < N) {
            float4 a = accs[i];
            float s1 = a.x * asv.x + a.y * asv.y + a.z * asv.z + a.w * asv.w;
            float s2 = a.x * adv.x + a.y * adv.y + a.z * adv.z + a.w * adv.w;
            #pragma unroll
            for (int o = 1; o < 16; o <<= 1) {
                s1 += __shfl_xor(s1, o, 64);
                s2 += __shfl_xor(s2, o, 64);
            }
            union { __half2 h2[2]; uint2 u; } pk;
            pk.h2[0] = __floats2half2_rn(a.x, a.y);
            pk.h2[1] = __floats2half2_rn(a.z, a.w);
            *(uint2*)&H[(size_t)row * 64 + tc * 4] = pk.u;
            if (tc == 0) { AS[row] = s1; AD[row] = s2; }
        }
    }
}

// ---------------- per-dst aggregation: 2 nodes per wave ----------------
template<int RELU, int NORM, int OUTH>
__global__ __launch_bounds__(256) void k_agg(
    const int* __restrict__ esrc, const int* __restrict__ offs,
    const __half* __restrict__ H, const float* __restrict__ AS,
    const float* __restrict__ AD, const float* __restrict__ bias,
    void* __restrict__ outv, int N)
{
    __shared__ int2 sm[4][64];
    int gid = blockIdx.x * blockDim.x + threadIdx.x;
    int w = gid >> 6;
    int lane = gid & 63;
    int wid = threadIdx.x >> 6;
    int n0 = 2 * w;
    if (n0 >= N) return;
    int half = lane >> 5, fp = lane & 31;
    int nh = n0 + half;
    bool valid = nh < N;
    int beg = valid ? offs[nh] : 0;
    int end = valid ? offs[nh + 1] : 0;
    int deg = end - beg;
    int degO = __shfl_xor(deg, 32, 64);
    int dm = max(deg, degO);
    float2 bp = ((const float2*)bias)[fp];

    if (dm <= 32) {
        float add = valid ? AD[nh] : 0.f;
        int s = 0;
        float logit = -3.0e38f;
        if (fp < deg) {
            s = esrc[beg + fp];
            float l0 = AS[s] + add;
            logit = (l0 > 0.f) ? l0 : 0.2f * l0;
        }
        float m = logit;
        #pragma unroll
        for (int o = 16; o > 0; o >>= 1) m = fmaxf(m, __shfl_xor(m, o, 64));
        float wg = (fp < deg) ? __expf(logit - m) : 0.f;
        float z = wg;
        #pragma unroll
        for (int o = 16; o > 0; o >>= 1) z += __shfl_xor(z, o, 64);
        sm[wid][lane] = make_int2(s, __float_as_int(wg));

        const __half2* H2 = (const __half2*)H;
        float2 a0 = {0.f, 0.f}, a1 = {0.f, 0.f};
        int base = half * 32;
        int k = 0;
        for (; k + 1 < dm; k += 2) {
            int4 v = *(const int4*)&sm[wid][base + k];
            float2 h0 = __half22float2(H2[(size_t)v.x * 32 + fp]);
            float2 h1 = __half22float2(H2[(size_t)v.z * 32 + fp]);
            float w0 = __int_as_float(v.y), w1 = __int_as_float(v.w);
            a0.x = fmaf(w0, h0.x, a0.x); a0.y = fmaf(w0, h0.y, a0.y);
            a1.x = fmaf(w1, h1.x, a1.x); a1.y = fmaf(w1, h1.y, a1.y);
        }
        if (k < dm) {
            int2 v = sm[wid][base + k];
            float2 h0 = __half22float2(H2[(size_t)v.x * 32 + fp]);
            float w0 = __int_as_float(v.y);
            a0.x = fmaf(w0, h0.x, a0.x); a0.y = fmaf(w0, h0.y, a0.y);
        }
        float2 acc = {a0.x + a1.x, a0.y + a1.y};
        float rz = (deg > 0) ? (1.0f / z) : 0.f;
        float2 val2 = make_float2(fmaf(acc.x, rz, bp.x), fmaf(acc.y, rz, bp.y));
        if (RELU) { val2.x = fmaxf(val2.x, 0.f); val2.y = fmaxf(val2.y, 0.f); }
        if (NORM) {
            float ss = val2.x * val2.x + val2.y * val2.y;
            #pragma unroll
            for (int o = 16; o > 0; o >>= 1) ss += __shfl_xor(ss, o, 64);
            float inv = 1.0f / fmaxf(sqrtf(ss), 1e-12f);
            val2.x *= inv; val2.y *= inv;
        }
        if (valid) {
            if (OUTH) ((__half2*)outv)[(size_t)nh * 32 + fp] = __floats2half2_rn(val2.x, val2.y);
            else      ((float2*)outv)[(size_t)nh * 32 + fp] = val2;
        }
        return;
    }

    // ---- rare fallback: per node with the full wave ----
    #pragma unroll 1
    for (int side = 0; side < 2; ++side) {
        int n = n0 + side;
        if (n >= N) break;
        int b2 = offs[n], e2 = offs[n + 1];
        int dg = e2 - b2;
        float add = AD[n];
        if (dg <= 64) {
            int s = 0;
            float logit = -3.0e38f;
            if (lane < dg) {
                s = esrc[b2 + lane];
                float l0 = AS[s] + add;
                logit = (l0 > 0.f) ? l0 : 0.2f * l0;
            }
            float m = logit;
            #pragma unroll
            for (int o = 32; o > 0; o >>= 1) m = fmaxf(m, __shfl_xor(m, o, 64));
            float wg = (lane < dg) ? __expf(logit - m) : 0.f;
            float z = wg;
            #pragma unroll
            for (int o = 32; o > 0; o >>= 1) z += __shfl_xor(z, o, 64);
            sm[wid][lane] = make_int2(s, __float_as_int(wg));
            const __half2* H2 = (const __half2*)H;
            float2 a0 = {0.f, 0.f};
            for (int k = half; k < dg; k += 2) {
                int2 v = sm[wid][k];
                float2 h0 = __half22float2(H2[(size_t)v.x * 32 + fp]);
                float w0 = __int_as_float(v.y);
                a0.x = fmaf(w0, h0.x, a0.x); a0.y = fmaf(w0, h0.y, a0.y);
            }
            a0.x += __shfl_xor(a0.x, 32, 64);
            a0.y += __shfl_xor(a0.y, 32, 64);
            float rz = (dg > 0) ? (1.0f / z) : 0.f;
            float2 val2 = make_float2(fmaf(a0.x, rz, bp.x), fmaf(a0.y, rz, bp.y));
            if (RELU) { val2.x = fmaxf(val2.x, 0.f); val2.y = fmaxf(val2.y, 0.f); }
            if (NORM) {
                float ss = val2.x * val2.x + val2.y * val2.y;
                #pragma unroll
                for (int o = 16; o > 0; o >>= 1) ss += __shfl_xor(ss, o, 64);
                float inv = 1.0f / fmaxf(sqrtf(ss), 1e-12f);
                val2.x *= inv; val2.y *= inv;
            }
            if (half == 0) {
                if (OUTH) ((__half2*)outv)[(size_t)n * 32 + fp] = __floats2half2_rn(val2.x, val2.y);
                else      ((float2*)outv)[(size_t)n * 32 + fp] = val2;
            }
        } else {
            float m = -3.0e38f, z = 0.f, acc = 0.f;
            for (int i = b2; i < e2; ++i) {
                int s = esrc[i];
                float l0 = AS[s] + add;
                l0 = (l0 > 0.f) ? l0 : 0.2f * l0;
                float mn = fmaxf(m, l0);
                float sc = __expf(m - mn);
                float wgt = __expf(l0 - mn);
                z = z * sc + wgt;
                acc = acc * sc + wgt * __half2float(H[(size_t)s * 64 + lane]);
                m = mn;
            }
            float val = acc / z + bias[lane];
            if (RELU) val = fmaxf(val, 0.f);
            if (NORM) {
                float ss = val * val;
                #pragma unroll
                for (int o = 32; o > 0; o >>= 1) ss += __shfl_xor(ss, o, 64);
                val = val / fmaxf(sqrtf(ss), 1e-12f);
            }
            if (OUTH) ((__half*)outv)[(size_t)n * 64 + lane] = __float2half(val);
            else      ((float*)outv)[(size_t)n * 64 + lane] = val;
        }
    }
}

// ---------------- launch ----------------

extern "C" void kernel_launch(void* const* d_in, const int* in_sizes, int n_in,
                              void* d_out, int out_size, void* d_ws, size_t ws_size,
                              hipStream_t stream) {
    const float* x   = (const float*)d_in[0];
    const int*   ei  = (const int*)d_in[1];
    const float* W1  = (const float*)d_in[2];
    const float* as1 = (const float*)d_in[3];
    const float* ad1 = (const float*)d_in[4];
    const float* b1  = (const float*)d_in[5];
    const float* W2  = (const float*)d_in[6];
    const float* as2 = (const float*)d_in[7];
    const float* ad2 = (const float*)d_in[8];
    const float* b2  = (const float*)d_in[9];
    const int* src = ei;
    const int* dst = ei + NEDGES;

    char* ws = (char*)d_ws;
    size_t off = 0;
    auto alloc = [&](size_t bytes) -> void* {
        void* p = ws + off;
        off = (off + bytes + 255) & ~(size_t)255;
        return p;
    };
    __half* H    = (__half*)alloc((size_t)NNODES * 64 * 2);
    __half* OUT1 = (__half*)alloc((size_t)NNODES * 64 * 2);
    float* AS    = (float*)alloc((size_t)NNODES * 4);
    float* AD    = (float*)alloc((size_t)NNODES * 4);
    int*   offs  = (int*)alloc((size_t)(NNODES + 1) * 4);
    int*   ep    = (int*)alloc((size_t)NEDGES * 4);
    int*   esrc  = (int*)alloc((size_t)NEDGES * 4);
    int*   bcnt  = (int*)alloc((size_t)SCANL * 4);
    int*   boffs = (int*)alloc((size_t)SCANL * 4);
    int*   part1 = (int*)alloc((size_t)SCANB * 4);

    // CSR build (dst identical for both layers) — no global atomics
    k_bcount<<<NBLK1, 256, 0, stream>>>(dst, bcnt);
    k_scan_block<<<SCANB, 1024, 0, stream>>>(bcnt, boffs, part1, SCANL);
    k_bscatter<<<NBLK1, 256, 0, stream>>>(src, dst, boffs, part1, ep);
    k_fine<<<NBUCK, 512, 0, stream>>>(ep, boffs, part1, offs, esrc);

    int aggBlocks = (NNODES / 2 + 3) / 4;  // 2 nodes/wave, 4 waves/block
    // Layer 1
    k_gemm_att<128, 0><<<(NNODES + 63) / 64, 256, 0, stream>>>(x, W1, as1, ad1, H, AS, AD, NNODES);
    k_agg<1, 0, 1><<<aggBlocks, 256, 0, stream>>>(esrc, offs, H, AS, AD, b1, OUT1, NNODES);

    // Layer 2
    k_gemm_att<64, 1><<<(NNODES + 63) / 64, 256, 0, stream>>>(OUT1, W2, as2, ad2, H, AS, AD, NNODES);
    k_agg<0, 1, 0><<<aggBlocks, 256, 0, stream>>>(esrc, offs, H, AS, AD, b2, d_out, NNODES);
}

// Round 10
// 117.036 us; speedup vs baseline: 3.0894x; 1.0102x over previous
//
#include <hip/hip_runtime.h>
#include <hip/hip_fp16.h>
#include <math.h>

#define NNODES 50000
#define NEDGES 800000
#define NBUCK 256
#define EPB 8192
#define NBLK1 ((NEDGES + EPB - 1) / EPB)      // 98
#define SCANL (NBUCK * NBLK1)                  // 25088
#define SCANB ((SCANL + 1023) / 1024)          // 25
#define FCAP 8192                              // per-bucket LDS sort capacity
#define NGEMM1 ((NNODES + 63) / 64)            // 782

// ---------------- CSR build: two-level bucket sort, LDS atomics only ----------------
// Edge record packed into int32: (src << 8) | (dst & 255).  src < 2^17, fits.

__global__ __launch_bounds__(256) void k_bcount(const int* __restrict__ dst,
                                                int* __restrict__ bcnt) {
    __shared__ int h[NBUCK];
    int t = threadIdx.x, b = blockIdx.x;
    h[t] = 0;
    __syncthreads();
    const int4* d4 = (const int4*)dst;
    int beg = b * (EPB / 4), end = min(beg + EPB / 4, NEDGES / 4);
    for (int e = beg + t; e < end; e += 256) {
        int4 v = d4[e];
        atomicAdd(&h[v.x >> 8], 1);
        atomicAdd(&h[v.y >> 8], 1);
        atomicAdd(&h[v.z >> 8], 1);
        atomicAdd(&h[v.w >> 8], 1);
    }
    __syncthreads();
    bcnt[t * NBLK1 + b] = h[t];
}

__global__ void k_scan_block(const int* __restrict__ in, int* __restrict__ out,
                             int* __restrict__ partial, int n) {
    __shared__ int tmp[1024];
    int t = threadIdx.x;
    int i = blockIdx.x * 1024 + t;
    int v = (i < n) ? in[i] : 0;
    tmp[t] = v;
    __syncthreads();
    for (int off = 1; off < 1024; off <<= 1) {
        int u = (t >= off) ? tmp[t - off] : 0;
        __syncthreads();
        tmp[t] += u;
        __syncthreads();
    }
    if (i < n) out[i] = tmp[t] - v;
    if (t == 1023) partial[blockIdx.x] = tmp[t];
}

__device__ __forceinline__ void scan_partials(const int* __restrict__ partial, int* sp) {
    int t = threadIdx.x;
    if (t < 64) {
        int v = (t < SCANB) ? partial[t] : 0;
        int incl = v;
        #pragma unroll
        for (int off = 1; off < 64; off <<= 1) {
            int u = __shfl_up(incl, off, 64);
            if (t >= off) incl += u;
        }
        if (t < SCANB) sp[t] = incl - v;
    }
    __syncthreads();
}

// ---------------- tiled SGEMM body (shared by fat kernel + standalone) ----------------

__device__ __forceinline__ void fma4(float4& a, float s, const float4& w) {
    a.x = fmaf(s, w.x, a.x);
    a.y = fmaf(s, w.y, a.y);
    a.z = fmaf(s, w.z, a.z);
    a.w = fmaf(s, w.w, a.w);
}

// XH: X is __half (64 wide); else float.
template<int K, int XH>
__device__ __forceinline__ void gemm_body(
    float* __restrict__ Xs, float* __restrict__ Ws, int bid,
    const void* __restrict__ Xv, const float* __restrict__ W,
    const float* __restrict__ a_src, const float* __restrict__ a_dst,
    __half* __restrict__ H, float* __restrict__ AS, float* __restrict__ AD, int N)
{
    constexpr int KF = K / 4;
    constexpr int KFS = (K == 128) ? 5 : 4;
    int t = threadIdx.x;
    int n0 = bid * 64;

    const float4* W4 = (const float4*)W;
    #pragma unroll
    for (int f = t; f < K * 16; f += 256)
        ((float4*)Ws)[f] = W4[f];
    #pragma unroll
    for (int f = t; f < 64 * KF; f += 256) {
        int r = f >> KFS, k4 = f & (KF - 1);
        float4 v = {0.f, 0.f, 0.f, 0.f};
        if (n0 + r < N) {
            if (XH) {
                union { uint2 u; __half2 h2[2]; } c;
                c.u = ((const uint2*)Xv)[(size_t)(n0 + r) * KF + k4];
                float2 lo = __half22float2(c.h2[0]);
                float2 hi = __half22float2(c.h2[1]);
                v = make_float4(lo.x, lo.y, hi.x, hi.y);
            } else {
                v = ((const float4*)Xv)[(size_t)(n0 + r) * KF + k4];
            }
        }
        ((float4*)&Xs[r * K])[k4 ^ ((r >> 2) & 3)] = v;
    }
    __syncthreads();

    int tr = t >> 4, tc = t & 15;
    int xi = tr & 3;
    const float4* xr0 = (const float4*)&Xs[(tr * 4 + 0) * K];
    const float4* xr1 = (const float4*)&Xs[(tr * 4 + 1) * K];
    const float4* xr2 = (const float4*)&Xs[(tr * 4 + 2) * K];
    const float4* xr3 = (const float4*)&Xs[(tr * 4 + 3) * K];
    float4 acc0 = {}, acc1 = {}, acc2 = {}, acc3 = {};

    #pragma unroll 2
    for (int k4 = 0; k4 < KF; ++k4) {
        int sl = k4 ^ xi;
        float4 x0 = xr0[sl], x1 = xr1[sl], x2 = xr2[sl], x3 = xr3[sl];
        float4 w0 = *(const float4*)&Ws[(k4 * 4 + 0) * 64 + tc * 4];
        float4 w1 = *(const float4*)&Ws[(k4 * 4 + 1) * 64 + tc * 4];
        float4 w2 = *(const float4*)&Ws[(k4 * 4 + 2) * 64 + tc * 4];
        float4 w3 = *(const float4*)&Ws[(k4 * 4 + 3) * 64 + tc * 4];
        fma4(acc0, x0.x, w0); fma4(acc0, x0.y, w1); fma4(acc0, x0.z, w2); fma4(acc0, x0.w, w3);
        fma4(acc1, x1.x, w0); fma4(acc1, x1.y, w1); fma4(acc1, x1.z, w2); fma4(acc1, x1.w, w3);
        fma4(acc2, x2.x, w0); fma4(acc2, x2.y, w1); fma4(acc2, x2.z, w2); fma4(acc2, x2.w, w3);
        fma4(acc3, x3.x, w0); fma4(acc3, x3.y, w1); fma4(acc3, x3.z, w2); fma4(acc3, x3.w, w3);
    }

    float4 asv = *(const float4*)&a_src[tc * 4];
    float4 adv = *(const float4*)&a_dst[tc * 4];
    float4 accs[4] = {acc0, acc1, acc2, acc3};
    #pragma unroll
    for (int i = 0; i < 4; ++i) {
        int row = n0 + tr * 4 + i;
        if (row < N) {
            float4 a = accs[i];
            float s1 = a.x * asv.x + a.y * asv.y + a.z * asv.z + a.w * asv.w;
            float s2 = a.x * adv.x + a.y * adv.y + a.z * adv.z + a.w * adv.w;
            #pragma unroll
            for (int o = 1; o < 16; o <<= 1) {
                s1 += __shfl_xor(s1, o, 64);
                s2 += __shfl_xor(s2, o, 64);
            }
            union { __half2 h2[2]; uint2 u; } pk;
            pk.h2[0] = __floats2half2_rn(a.x, a.y);
            pk.h2[1] = __floats2half2_rn(a.z, a.w);
            *(uint2*)&H[(size_t)row * 64 + tc * 4] = pk.u;
            if (tc == 0) { AS[row] = s1; AD[row] = s2; }
        }
    }
}

// standalone GEMM (layer 2): 32 KB LDS -> 3 blocks/CU
template<int K, int XH, int MINW>
__global__ __launch_bounds__(256, MINW) void k_gemm_att(
    const void* __restrict__ Xv, const float* __restrict__ W,
    const float* __restrict__ a_src, const float* __restrict__ a_dst,
    __half* __restrict__ H, float* __restrict__ AS, float* __restrict__ AD, int N)
{
    __shared__ float Xs[64 * K];
    __shared__ float Ws[K * 64];
    gemm_body<K, XH>(Xs, Ws, blockIdx.x, Xv, W, a_src, a_dst, H, AS, AD, N);
}

// ---------------- fat kernel: gemm1 blocks [0,NGEMM1) || bscatter blocks after ----------------

__global__ __launch_bounds__(256, 2) void k_gemm1_bscatter(
    const float* __restrict__ X, const float* __restrict__ W1,
    const float* __restrict__ as1, const float* __restrict__ ad1,
    __half* __restrict__ H, float* __restrict__ AS, float* __restrict__ AD,
    const int* __restrict__ src, const int* __restrict__ dst,
    const int* __restrict__ boffs, const int* __restrict__ partial,
    int* __restrict__ ep)
{
    __shared__ float Xs[64 * 128];
    __shared__ float Ws[128 * 64];
    if (blockIdx.x < NGEMM1) {
        gemm_body<128, 0>(Xs, Ws, blockIdx.x, X, W1, as1, ad1, H, AS, AD, NNODES);
        return;
    }
    // bscatter role (LDS overlaid onto gemm staging buffers)
    int* cur = (int*)Xs;
    int* sp  = (int*)Ws;
    int t = threadIdx.x, b = blockIdx.x - NGEMM1;
    scan_partials(partial, sp);
    int idx = t * NBLK1 + b;
    cur[t] = boffs[idx] + sp[idx >> 10];
    __syncthreads();
    int beg = b * EPB, end = min(beg + EPB, NEDGES);
    for (int e = beg + t; e < end; e += 256) {
        int d = dst[e];
        int pos = atomicAdd(&cur[d >> 8], 1);
        ep[pos] = (src[e] << 8) | (d & 255);
    }
}

// per-bucket fine CSR via in-LDS counting sort; coalesced esrc writes
__global__ __launch_bounds__(512) void k_fine(const int* __restrict__ ep,
                                              const int* __restrict__ boffs,
                                              const int* __restrict__ partial,
                                              int* __restrict__ offs,
                                              int* __restrict__ esrc) {
    __shared__ int h[NBUCK];
    __shared__ int cur[NBUCK];
    __shared__ int sp[SCANB];
    __shared__ int stg[FCAP];
    __shared__ int srt[FCAP];
    int t = threadIdx.x, buck = blockIdx.x;
    scan_partials(partial, sp);
    int bi = buck * NBLK1;
    int base = boffs[bi] + sp[bi >> 10];
    int endp;
    if (buck == NBUCK - 1) endp = NEDGES;
    else {
        int ei2 = (buck + 1) * NBLK1;
        endp = boffs[ei2] + sp[ei2 >> 10];
    }
    int cnt = endp - base;
    bool fits = (cnt <= FCAP);

    if (t < NBUCK) h[t] = 0;
    __syncthreads();
    if (fits) {
        for (int j = t; j < cnt; j += 512) stg[j] = ep[base + j];   // coalesced, once
        __syncthreads();
        for (int j = t; j < cnt; j += 512) atomicAdd(&h[stg[j] & 255], 1);
    } else {
        for (int i = base + t; i < endp; i += 512) atomicAdd(&h[ep[i] & 255], 1);
    }
    __syncthreads();
    int v = (t < NBUCK) ? h[t] : 0;
    for (int off = 1; off < 256; off <<= 1) {
        int u = (t >= off && t < NBUCK) ? h[t - off] : 0;
        __syncthreads();
        if (t < NBUCK) h[t] += u;
        __syncthreads();
    }
    if (t < NBUCK) {
        int excl = h[t] - v;
        int node = buck * 256 + t;
        if (node <= NNODES) offs[node] = base + excl;
        cur[t] = excl;                                   // local offsets
    }
    __syncthreads();
    if (fits) {
        for (int j = t; j < cnt; j += 512) {
            int p = stg[j];
            int pos = atomicAdd(&cur[p & 255], 1);
            srt[pos] = p >> 8;                           // LDS counting sort
        }
        __syncthreads();
        for (int j = t; j < cnt; j += 512) esrc[base + j] = srt[j];  // coalesced
    } else {
        for (int i = base + t; i < endp; i += 512) {
            int p = ep[i];
            int pos = atomicAdd(&cur[p & 255], 1);
            esrc[base + pos] = p >> 8;
        }
    }
}

// ---------------- per-dst aggregation: 2 nodes per wave ----------------
template<int RELU, int NORM, int OUTH>
__global__ __launch_bounds__(256) void k_agg(
    const int* __restrict__ esrc, const int* __restrict__ offs,
    const __half* __restrict__ H, const float* __restrict__ AS,
    const float* __restrict__ AD, const float* __restrict__ bias,
    void* __restrict__ outv, int N)
{
    __shared__ int2 sm[4][64];
    int gid = blockIdx.x * blockDim.x + threadIdx.x;
    int w = gid >> 6;
    int lane = gid & 63;
    int wid = threadIdx.x >> 6;
    int n0 = 2 * w;
    if (n0 >= N) return;
    int half = lane >> 5, fp = lane & 31;
    int nh = n0 + half;
    bool valid = nh < N;
    int beg = valid ? offs[nh] : 0;
    int end = valid ? offs[nh + 1] : 0;
    int deg = end - beg;
    int degO = __shfl_xor(deg, 32, 64);
    int dm = max(deg, degO);
    float2 bp = ((const float2*)bias)[fp];

    if (dm <= 32) {
        float add = valid ? AD[nh] : 0.f;
        int s = 0;
        float logit = -3.0e38f;
        if (fp < deg) {
            s = esrc[beg + fp];
            float l0 = AS[s] + add;
            logit = (l0 > 0.f) ? l0 : 0.2f * l0;
        }
        float m = logit;
        #pragma unroll
        for (int o = 16; o > 0; o >>= 1) m = fmaxf(m, __shfl_xor(m, o, 64));
        float wg = (fp < deg) ? __expf(logit - m) : 0.f;
        float z = wg;
        #pragma unroll
        for (int o = 16; o > 0; o >>= 1) z += __shfl_xor(z, o, 64);
        sm[wid][lane] = make_int2(s, __float_as_int(wg));

        const __half2* H2 = (const __half2*)H;
        float2 a0 = {0.f, 0.f}, a1 = {0.f, 0.f};
        int base = half * 32;
        int k = 0;
        for (; k + 1 < dm; k += 2) {
            int4 v = *(const int4*)&sm[wid][base + k];
            float2 h0 = __half22float2(H2[(size_t)v.x * 32 + fp]);
            float2 h1 = __half22float2(H2[(size_t)v.z * 32 + fp]);
            float w0 = __int_as_float(v.y), w1 = __int_as_float(v.w);
            a0.x = fmaf(w0, h0.x, a0.x); a0.y = fmaf(w0, h0.y, a0.y);
            a1.x = fmaf(w1, h1.x, a1.x); a1.y = fmaf(w1, h1.y, a1.y);
        }
        if (k < dm) {
            int2 v = sm[wid][base + k];
            float2 h0 = __half22float2(H2[(size_t)v.x * 32 + fp]);
            float w0 = __int_as_float(v.y);
            a0.x = fmaf(w0, h0.x, a0.x); a0.y = fmaf(w0, h0.y, a0.y);
        }
        float2 acc = {a0.x + a1.x, a0.y + a1.y};
        float rz = (deg > 0) ? (1.0f / z) : 0.f;
        float2 val2 = make_float2(fmaf(acc.x, rz, bp.x), fmaf(acc.y, rz, bp.y));
        if (RELU) { val2.x = fmaxf(val2.x, 0.f); val2.y = fmaxf(val2.y, 0.f); }
        if (NORM) {
            float ss = val2.x * val2.x + val2.y * val2.y;
            #pragma unroll
            for (int o = 16; o > 0; o >>= 1) ss += __shfl_xor(ss, o, 64);
            float inv = 1.0f / fmaxf(sqrtf(ss), 1e-12f);
            val2.x *= inv; val2.y *= inv;
        }
        if (valid) {
            if (OUTH) ((__half2*)outv)[(size_t)nh * 32 + fp] = __floats2half2_rn(val2.x, val2.y);
            else      ((float2*)outv)[(size_t)nh * 32 + fp] = val2;
        }
        return;
    }

    // ---- rare fallback: per node with the full wave ----
    #pragma unroll 1
    for (int side = 0; side < 2; ++side) {
        int n = n0 + side;
        if (n >= N) break;
        int b2 = offs[n], e2 = offs[n + 1];
        int dg = e2 - b2;
        float add = AD[n];
        if (dg <= 64) {
            int s = 0;
            float logit = -3.0e38f;
            if (lane < dg) {
                s = esrc[b2 + lane];
                float l0 = AS[s] + add;
                logit = (l0 > 0.f) ? l0 : 0.2f * l0;
            }
            float m = logit;
            #pragma unroll
            for (int o = 32; o > 0; o >>= 1) m = fmaxf(m, __shfl_xor(m, o, 64));
            float wg = (lane < dg) ? __expf(logit - m) : 0.f;
            float z = wg;
            #pragma unroll
            for (int o = 32; o > 0; o >>= 1) z += __shfl_xor(z, o, 64);
            sm[wid][lane] = make_int2(s, __float_as_int(wg));
            const __half2* H2 = (const __half2*)H;
            float2 a0 = {0.f, 0.f};
            for (int k = half; k < dg; k += 2) {
                int2 v = sm[wid][k];
                float2 h0 = __half22float2(H2[(size_t)v.x * 32 + fp]);
                float w0 = __int_as_float(v.y);
                a0.x = fmaf(w0, h0.x, a0.x); a0.y = fmaf(w0, h0.y, a0.y);
            }
            a0.x += __shfl_xor(a0.x, 32, 64);
            a0.y += __shfl_xor(a0.y, 32, 64);
            float rz = (dg > 0) ? (1.0f / z) : 0.f;
            float2 val2 = make_float2(fmaf(a0.x, rz, bp.x), fmaf(a0.y, rz, bp.y));
            if (RELU) { val2.x = fmaxf(val2.x, 0.f); val2.y = fmaxf(val2.y, 0.f); }
            if (NORM) {
                float ss = val2.x * val2.x + val2.y * val2.y;
                #pragma unroll
                for (int o = 16; o > 0; o >>= 1) ss += __shfl_xor(ss, o, 64);
                float inv = 1.0f / fmaxf(sqrtf(ss), 1e-12f);
                val2.x *= inv; val2.y *= inv;
            }
            if (half == 0) {
                if (OUTH) ((__half2*)outv)[(size_t)n * 32 + fp] = __floats2half2_rn(val2.x, val2.y);
                else      ((float2*)outv)[(size_t)n * 32 + fp] = val2;
            }
        } else {
            float m = -3.0e38f, z = 0.f, acc = 0.f;
            for (int i = b2; i < e2; ++i) {
                int s = esrc[i];
                float l0 = AS[s] + add;
                l0 = (l0 > 0.f) ? l0 : 0.2f * l0;
                float mn = fmaxf(m, l0);
                float sc = __expf(m - mn);
                float wgt = __expf(l0 - mn);
                z = z * sc + wgt;
                acc = acc * sc + wgt * __half2float(H[(size_t)s * 64 + lane]);
                m = mn;
            }
            float val = acc / z + bias[lane];
            if (RELU) val = fmaxf(val, 0.f);
            if (NORM) {
                float ss = val * val;
                #pragma unroll
                for (int o = 32; o > 0; o >>= 1) ss += __shfl_xor(ss, o, 64);
                val = val / fmaxf(sqrtf(ss), 1e-12f);
            }
            if (OUTH) ((__half*)outv)[(size_t)n * 64 + lane] = __float2half(val);
            else      ((float*)outv)[(size_t)n * 64 + lane] = val;
        }
    }
}

// ---------------- launch ----------------

extern "C" void kernel_launch(void* const* d_in, const int* in_sizes, int n_in,
                              void* d_out, int out_size, void* d_ws, size_t ws_size,
                              hipStream_t stream) {
    const float* x   = (const float*)d_in[0];
    const int*   ei  = (const int*)d_in[1];
    const float* W1  = (const float*)d_in[2];
    const float* as1 = (const float*)d_in[3];
    const float* ad1 = (const float*)d_in[4];
    const float* b1  = (const float*)d_in[5];
    const float* W2  = (const float*)d_in[6];
    const float* as2 = (const float*)d_in[7];
    const float* ad2 = (const float*)d_in[8];
    const float* b2  = (const float*)d_in[9];
    const int* src = ei;
    const int* dst = ei + NEDGES;

    char* ws = (char*)d_ws;
    size_t off = 0;
    auto alloc = [&](size_t bytes) -> void* {
        void* p = ws + off;
        off = (off + bytes + 255) & ~(size_t)255;
        return p;
    };
    __half* H    = (__half*)alloc((size_t)NNODES * 64 * 2);
    __half* OUT1 = (__half*)alloc((size_t)NNODES * 64 * 2);
    float* AS    = (float*)alloc((size_t)NNODES * 4);
    float* AD    = (float*)alloc((size_t)NNODES * 4);
    int*   offs  = (int*)alloc((size_t)(NNODES + 1) * 4);
    int*   ep    = (int*)alloc((size_t)NEDGES * 4);
    int*   esrc  = (int*)alloc((size_t)NEDGES * 4);
    int*   bcnt  = (int*)alloc((size_t)SCANL * 4);
    int*   boffs = (int*)alloc((size_t)SCANL * 4);
    int*   part1 = (int*)alloc((size_t)SCANB * 4);

    // CSR build (dst identical for both layers) — no global atomics
    k_bcount<<<NBLK1, 256, 0, stream>>>(dst, bcnt);
    k_scan_block<<<SCANB, 1024, 0, stream>>>(bcnt, boffs, part1, SCANL);
    // fused: gemm1 (blocks [0,782)) concurrent with bscatter (blocks [782,880))
    k_gemm1_bscatter<<<NGEMM1 + NBLK1, 256, 0, stream>>>(
        x, W1, as1, ad1, H, AS, AD, src, dst, boffs, part1, ep);
    k_fine<<<NBUCK, 512, 0, stream>>>(ep, boffs, part1, offs, esrc);

    int aggBlocks = (NNODES / 2 + 3) / 4;  // 2 nodes/wave, 4 waves/block
    // Layer 1 aggregation
    k_agg<1, 0, 1><<<aggBlocks, 256, 0, stream>>>(esrc, offs, H, AS, AD, b1, OUT1, NNODES);

    // Layer 2
    k_gemm_att<64, 1, 3><<<(NNODES + 63) / 64, 256, 0, stream>>>(OUT1, W2, as2, ad2, H, AS, AD, NNODES);
    k_agg<0, 1, 0><<<aggBlocks, 256, 0, stream>>>(esrc, offs, H, AS, AD, b2, d_out, NNODES);
}

// Round 11
// 105.317 us; speedup vs baseline: 3.4331x; 1.1113x over previous
//
#include <hip/hip_runtime.h>
#include <hip/hip_fp16.h>
#include <math.h>

#define NNODES 50000
#define NEDGES 800000
#define NBUCK 256
#define EPB 8192
#define NBLK1 ((NEDGES + EPB - 1) / EPB)      // 98
#define SCANL (NBUCK * NBLK1)                  // 25088
#define SCANB ((SCANL + 1023) / 1024)          // 25
#define FCAP 8192                              // per-bucket LDS sort capacity
#define NGEMM1 ((NNODES + 63) / 64)            // 782

typedef _Float16 f16;
typedef _Float16 f16x4 __attribute__((ext_vector_type(4)));
typedef _Float16 f16x8 __attribute__((ext_vector_type(8)));
typedef float    f32x4 __attribute__((ext_vector_type(4)));

// ---------------- CSR build: two-level bucket sort, LDS atomics only ----------------
// Edge record packed into int32: (src << 8) | (dst & 255).  src < 2^17, fits.
// Blocks [NBLK1, NBLK1+2) double as W-prep: W^T -> fp16, swizzle baked in.

__global__ __launch_bounds__(256) void k_bcount(const int* __restrict__ dst,
                                                int* __restrict__ bcnt,
                                                const float* __restrict__ W1,
                                                const float* __restrict__ W2,
                                                __half* __restrict__ Wt1,
                                                __half* __restrict__ Wt2) {
    __shared__ int h[NBUCK];
    int t = threadIdx.x, b = blockIdx.x;
    if (b >= NBLK1) {
        if (b == NBLK1) {
            for (int idx = t; idx < 128 * 64; idx += 256) {
                int k = idx >> 6, col = idx & 63;
                Wt1[col * 128 + (k ^ ((col & 7) << 3))] = __float2half(W1[idx]);
            }
        } else {
            for (int idx = t; idx < 64 * 64; idx += 256) {
                int k = idx >> 6, col = idx & 63;
                Wt2[col * 64 + (k ^ ((col & 7) << 3))] = __float2half(W2[idx]);
            }
        }
        return;
    }
    h[t] = 0;
    __syncthreads();
    const int4* d4 = (const int4*)dst;
    int beg = b * (EPB / 4), end = min(beg + EPB / 4, NEDGES / 4);
    for (int e = beg + t; e < end; e += 256) {
        int4 v = d4[e];
        atomicAdd(&h[v.x >> 8], 1);
        atomicAdd(&h[v.y >> 8], 1);
        atomicAdd(&h[v.z >> 8], 1);
        atomicAdd(&h[v.w >> 8], 1);
    }
    __syncthreads();
    bcnt[t * NBLK1 + b] = h[t];
}

__global__ void k_scan_block(const int* __restrict__ in, int* __restrict__ out,
                             int* __restrict__ partial, int n) {
    __shared__ int tmp[1024];
    int t = threadIdx.x;
    int i = blockIdx.x * 1024 + t;
    int v = (i < n) ? in[i] : 0;
    tmp[t] = v;
    __syncthreads();
    for (int off = 1; off < 1024; off <<= 1) {
        int u = (t >= off) ? tmp[t - off] : 0;
        __syncthreads();
        tmp[t] += u;
        __syncthreads();
    }
    if (i < n) out[i] = tmp[t] - v;
    if (t == 1023) partial[blockIdx.x] = tmp[t];
}

__device__ __forceinline__ void scan_partials(const int* __restrict__ partial, int* sp) {
    int t = threadIdx.x;
    if (t < 64) {
        int v = (t < SCANB) ? partial[t] : 0;
        int incl = v;
        #pragma unroll
        for (int off = 1; off < 64; off <<= 1) {
            int u = __shfl_up(incl, off, 64);
            if (t >= off) incl += u;
        }
        if (t < SCANB) sp[t] = incl - v;
    }
    __syncthreads();
}

// ---------------- MFMA GEMM body (16x16x32 f16, fp32 accum) ----------------
// Block = 256 thr = 4 waves; tile 64 rows x 64 cols; wave w -> rows w*16..+16.
// Xs: [64][K] fp16, XOR-swizzled ((row&7)<<4 on byte offset).
// Ws: W^T [64 cols][K] fp16, same swizzle (pre-baked in global WtSwz).
// A-frag: row=lane&15, k=(lane>>4)*8+j.  B-frag: col=lane&15, same k.
// C/D:    col=lane&15, row=(lane>>4)*4+reg   [m89-verified].

template<int K, int XH>
__device__ __forceinline__ void gemm_body(
    __half* __restrict__ Xs_h, __half* __restrict__ Ws_h, int bid,
    const void* __restrict__ Xv, const __half* __restrict__ WtSwz,
    const float* __restrict__ a_src, const float* __restrict__ a_dst,
    __half* __restrict__ H, float* __restrict__ AS, float* __restrict__ AD, int N)
{
    constexpr int KF = K / 4;                 // 4-element groups per row
    constexpr int KFS = (K == 128) ? 5 : 4;   // log2(KF)
    int t = threadIdx.x;
    int n0 = bid * 64;

    // stage W^T (pre-swizzled fp16): linear copy
    {
        const uint2* wsrc = (const uint2*)WtSwz;
        uint2* wdst = (uint2*)Ws_h;
        #pragma unroll
        for (int f = t; f < K * 16; f += 256) wdst[f] = wsrc[f];  // K*64 halves / 4
    }
    // stage X tile -> fp16, swizzled 8B writes
    #pragma unroll
    for (int f = t; f < 64 * KF; f += 256) {
        int r = f >> KFS, k4 = f & (KF - 1);
        f16x4 hv = {0, 0, 0, 0};
        if (n0 + r < N) {
            if (XH) {
                union { uint2 u; f16x4 h4; } c;
                c.u = ((const uint2*)Xv)[(size_t)(n0 + r) * KF + k4];
                hv = c.h4;
            } else {
                float4 v = ((const float4*)Xv)[(size_t)(n0 + r) * KF + k4];
                hv[0] = (f16)v.x; hv[1] = (f16)v.y; hv[2] = (f16)v.z; hv[3] = (f16)v.w;
            }
        }
        int bo = (k4 * 8) ^ ((r & 7) << 4);
        *(f16x4*)((char*)Xs_h + r * (K * 2) + bo) = hv;
    }
    __syncthreads();

    int w = t >> 6, l = t & 63;
    int lg = l >> 4, l15 = l & 15;
    int rA = w * 16 + l15;                    // A row (tile-local)
    int sw = (l15 & 7) << 4;                  // swizzle (same for A and B: 16≡0 mod 8)

    f32x4 acc[4];
    #pragma unroll
    for (int ct = 0; ct < 4; ++ct) acc[ct] = (f32x4){0.f, 0.f, 0.f, 0.f};

    const char* pA = (const char*)Xs_h + rA * (K * 2);
    #pragma unroll
    for (int ks = 0; ks < K / 32; ++ks) {
        int ko = ks * 64 + (lg << 4);
        f16x8 a = *(const f16x8*)(pA + (ko ^ sw));
        #pragma unroll
        for (int ct = 0; ct < 4; ++ct) {
            const char* pB = (const char*)Ws_h + (ct * 16 + l15) * (K * 2) + (ko ^ sw);
            f16x8 bfr = *(const f16x8*)pB;
            acc[ct] = __builtin_amdgcn_mfma_f32_16x16x32_f16(a, bfr, acc[ct], 0, 0, 0);
        }
    }

    // epilogue: H (fp16) + attention logits
    float asv[4], adv[4];
    #pragma unroll
    for (int ct = 0; ct < 4; ++ct) {
        asv[ct] = a_src[ct * 16 + l15];
        adv[ct] = a_dst[ct * 16 + l15];
    }
    #pragma unroll
    for (int reg = 0; reg < 4; ++reg) {
        int row = n0 + w * 16 + lg * 4 + reg;
        if (row < N) {
            float s1 = 0.f, s2 = 0.f;
            #pragma unroll
            for (int ct = 0; ct < 4; ++ct) {
                s1 = fmaf(acc[ct][reg], asv[ct], s1);
                s2 = fmaf(acc[ct][reg], adv[ct], s2);
            }
            #pragma unroll
            for (int o = 1; o < 16; o <<= 1) {
                s1 += __shfl_xor(s1, o, 64);
                s2 += __shfl_xor(s2, o, 64);
            }
            #pragma unroll
            for (int ct = 0; ct < 4; ++ct)
                H[(size_t)row * 64 + ct * 16 + l15] = __float2half(acc[ct][reg]);
            if (l15 == 0) { AS[row] = s1; AD[row] = s2; }
        }
    }
}

// standalone GEMM (layer 2)
template<int K, int XH>
__global__ __launch_bounds__(256, 4) void k_gemm_att(
    const void* __restrict__ Xv, const __half* __restrict__ WtSwz,
    const float* __restrict__ a_src, const float* __restrict__ a_dst,
    __half* __restrict__ H, float* __restrict__ AS, float* __restrict__ AD, int N)
{
    __shared__ __align__(16) __half Xs[64 * K];
    __shared__ __align__(16) __half Ws[64 * K];
    gemm_body<K, XH>(Xs, Ws, blockIdx.x, Xv, WtSwz, a_src, a_dst, H, AS, AD, N);
}

// ---------------- fat kernel: gemm1 blocks [0,NGEMM1) || bscatter after ----------------

__global__ __launch_bounds__(256, 4) void k_gemm1_bscatter(
    const float* __restrict__ X, const __half* __restrict__ Wt1,
    const float* __restrict__ as1, const float* __restrict__ ad1,
    __half* __restrict__ H, float* __restrict__ AS, float* __restrict__ AD,
    const int* __restrict__ src, const int* __restrict__ dst,
    const int* __restrict__ boffs, const int* __restrict__ partial,
    int* __restrict__ ep)
{
    __shared__ __align__(16) __half Xs[64 * 128];
    __shared__ __align__(16) __half Ws[64 * 128];
    if (blockIdx.x < NGEMM1) {
        gemm_body<128, 0>(Xs, Ws, blockIdx.x, X, Wt1, as1, ad1, H, AS, AD, NNODES);
        return;
    }
    // bscatter role (LDS overlaid)
    int* cur = (int*)Xs;
    int* sp  = (int*)Ws;
    int t = threadIdx.x, b = blockIdx.x - NGEMM1;
    scan_partials(partial, sp);
    int idx = t * NBLK1 + b;
    cur[t] = boffs[idx] + sp[idx >> 10];
    __syncthreads();
    int beg = b * EPB, end = min(beg + EPB, NEDGES);
    for (int e = beg + t; e < end; e += 256) {
        int d = dst[e];
        int pos = atomicAdd(&cur[d >> 8], 1);
        ep[pos] = (src[e] << 8) | (d & 255);
    }
}

// per-bucket fine CSR via in-LDS counting sort; coalesced esrc writes
__global__ __launch_bounds__(512) void k_fine(const int* __restrict__ ep,
                                              const int* __restrict__ boffs,
                                              const int* __restrict__ partial,
                                              int* __restrict__ offs,
                                              int* __restrict__ esrc) {
    __shared__ int h[NBUCK];
    __shared__ int cur[NBUCK];
    __shared__ int sp[SCANB];
    __shared__ int stg[FCAP];
    __shared__ int srt[FCAP];
    int t = threadIdx.x, buck = blockIdx.x;
    scan_partials(partial, sp);
    int bi = buck * NBLK1;
    int base = boffs[bi] + sp[bi >> 10];
    int endp;
    if (buck == NBUCK - 1) endp = NEDGES;
    else {
        int ei2 = (buck + 1) * NBLK1;
        endp = boffs[ei2] + sp[ei2 >> 10];
    }
    int cnt = endp - base;
    bool fits = (cnt <= FCAP);

    if (t < NBUCK) h[t] = 0;
    __syncthreads();
    if (fits) {
        for (int j = t; j < cnt; j += 512) stg[j] = ep[base + j];
        __syncthreads();
        for (int j = t; j < cnt; j += 512) atomicAdd(&h[stg[j] & 255], 1);
    } else {
        for (int i = base + t; i < endp; i += 512) atomicAdd(&h[ep[i] & 255], 1);
    }
    __syncthreads();
    int v = (t < NBUCK) ? h[t] : 0;
    for (int off = 1; off < 256; off <<= 1) {
        int u = (t >= off && t < NBUCK) ? h[t - off] : 0;
        __syncthreads();
        if (t < NBUCK) h[t] += u;
        __syncthreads();
    }
    if (t < NBUCK) {
        int excl = h[t] - v;
        int node = buck * 256 + t;
        if (node <= NNODES) offs[node] = base + excl;
        cur[t] = excl;
    }
    __syncthreads();
    if (fits) {
        for (int j = t; j < cnt; j += 512) {
            int p = stg[j];
            int pos = atomicAdd(&cur[p & 255], 1);
            srt[pos] = p >> 8;
        }
        __syncthreads();
        for (int j = t; j < cnt; j += 512) esrc[base + j] = srt[j];
    } else {
        for (int i = base + t; i < endp; i += 512) {
            int p = ep[i];
            int pos = atomicAdd(&cur[p & 255], 1);
            esrc[base + pos] = p >> 8;
        }
    }
}

// ---------------- per-dst aggregation: 2 nodes per wave ----------------
template<int RELU, int NORM, int OUTH>
__global__ __launch_bounds__(256) void k_agg(
    const int* __restrict__ esrc, const int* __restrict__ offs,
    const __half* __restrict__ H, const float* __restrict__ AS,
    const float* __restrict__ AD, const float* __restrict__ bias,
    void* __restrict__ outv, int N)
{
    __shared__ int2 sm[4][64];
    int gid = blockIdx.x * blockDim.x + threadIdx.x;
    int w = gid >> 6;
    int lane = gid & 63;
    int wid = threadIdx.x >> 6;
    int n0 = 2 * w;
    if (n0 >= N) return;
    int half = lane >> 5, fp = lane & 31;
    int nh = n0 + half;
    bool valid = nh < N;
    int beg = valid ? offs[nh] : 0;
    int end = valid ? offs[nh + 1] : 0;
    int deg = end - beg;
    int degO = __shfl_xor(deg, 32, 64);
    int dm = max(deg, degO);
    float2 bp = ((const float2*)bias)[fp];

    if (dm <= 32) {
        float add = valid ? AD[nh] : 0.f;
        int s = 0;
        float logit = -3.0e38f;
        if (fp < deg) {
            s = esrc[beg + fp];
            float l0 = AS[s] + add;
            logit = (l0 > 0.f) ? l0 : 0.2f * l0;
        }
        float m = logit;
        #pragma unroll
        for (int o = 16; o > 0; o >>= 1) m = fmaxf(m, __shfl_xor(m, o, 64));
        float wg = (fp < deg) ? __expf(logit - m) : 0.f;
        float z = wg;
        #pragma unroll
        for (int o = 16; o > 0; o >>= 1) z += __shfl_xor(z, o, 64);
        sm[wid][lane] = make_int2(s, __float_as_int(wg));

        const __half2* H2 = (const __half2*)H;
        float2 a0 = {0.f, 0.f}, a1 = {0.f, 0.f};
        int base = half * 32;
        int k = 0;
        for (; k + 1 < dm; k += 2) {
            int4 v = *(const int4*)&sm[wid][base + k];
            float2 h0 = __half22float2(H2[(size_t)v.x * 32 + fp]);
            float2 h1 = __half22float2(H2[(size_t)v.z * 32 + fp]);
            float w0 = __int_as_float(v.y), w1 = __int_as_float(v.w);
            a0.x = fmaf(w0, h0.x, a0.x); a0.y = fmaf(w0, h0.y, a0.y);
            a1.x = fmaf(w1, h1.x, a1.x); a1.y = fmaf(w1, h1.y, a1.y);
        }
        if (k < dm) {
            int2 v = sm[wid][base + k];
            float2 h0 = __half22float2(H2[(size_t)v.x * 32 + fp]);
            float w0 = __int_as_float(v.y);
            a0.x = fmaf(w0, h0.x, a0.x); a0.y = fmaf(w0, h0.y, a0.y);
        }
        float2 acc = {a0.x + a1.x, a0.y + a1.y};
        float rz = (deg > 0) ? (1.0f / z) : 0.f;
        float2 val2 = make_float2(fmaf(acc.x, rz, bp.x), fmaf(acc.y, rz, bp.y));
        if (RELU) { val2.x = fmaxf(val2.x, 0.f); val2.y = fmaxf(val2.y, 0.f); }
        if (NORM) {
            float ss = val2.x * val2.x + val2.y * val2.y;
            #pragma unroll
            for (int o = 16; o > 0; o >>= 1) ss += __shfl_xor(ss, o, 64);
            float inv = 1.0f / fmaxf(sqrtf(ss), 1e-12f);
            val2.x *= inv; val2.y *= inv;
        }
        if (valid) {
            if (OUTH) ((__half2*)outv)[(size_t)nh * 32 + fp] = __floats2half2_rn(val2.x, val2.y);
            else      ((float2*)outv)[(size_t)nh * 32 + fp] = val2;
        }
        return;
    }

    // ---- rare fallback: per node with the full wave ----
    #pragma unroll 1
    for (int side = 0; side < 2; ++side) {
        int n = n0 + side;
        if (n >= N) break;
        int b2 = offs[n], e2 = offs[n + 1];
        int dg = e2 - b2;
        float add = AD[n];
        if (dg <= 64) {
            int s = 0;
            float logit = -3.0e38f;
            if (lane < dg) {
                s = esrc[b2 + lane];
                float l0 = AS[s] + add;
                logit = (l0 > 0.f) ? l0 : 0.2f * l0;
            }
            float m = logit;
            #pragma unroll
            for (int o = 32; o > 0; o >>= 1) m = fmaxf(m, __shfl_xor(m, o, 64));
            float wg = (lane < dg) ? __expf(logit - m) : 0.f;
            float z = wg;
            #pragma unroll
            for (int o = 32; o > 0; o >>= 1) z += __shfl_xor(z, o, 64);
            sm[wid][lane] = make_int2(s, __float_as_int(wg));
            const __half2* H2 = (const __half2*)H;
            float2 a0 = {0.f, 0.f};
            for (int k = half; k < dg; k += 2) {
                int2 v = sm[wid][k];
                float2 h0 = __half22float2(H2[(size_t)v.x * 32 + fp]);
                float w0 = __int_as_float(v.y);
                a0.x = fmaf(w0, h0.x, a0.x); a0.y = fmaf(w0, h0.y, a0.y);
            }
            a0.x += __shfl_xor(a0.x, 32, 64);
            a0.y += __shfl_xor(a0.y, 32, 64);
            float rz = (dg > 0) ? (1.0f / z) : 0.f;
            float2 val2 = make_float2(fmaf(a0.x, rz, bp.x), fmaf(a0.y, rz, bp.y));
            if (RELU) { val2.x = fmaxf(val2.x, 0.f); val2.y = fmaxf(val2.y, 0.f); }
            if (NORM) {
                float ss = val2.x * val2.x + val2.y * val2.y;
                #pragma unroll
                for (int o = 16; o > 0; o >>= 1) ss += __shfl_xor(ss, o, 64);
                float inv = 1.0f / fmaxf(sqrtf(ss), 1e-12f);
                val2.x *= inv; val2.y *= inv;
            }
            if (half == 0) {
                if (OUTH) ((__half2*)outv)[(size_t)n * 32 + fp] = __floats2half2_rn(val2.x, val2.y);
                else      ((float2*)outv)[(size_t)n * 32 + fp] = val2;
            }
        } else {
            float m = -3.0e38f, z = 0.f, acc = 0.f;
            for (int i = b2; i < e2; ++i) {
                int s = esrc[i];
                float l0 = AS[s] + add;
                l0 = (l0 > 0.f) ? l0 : 0.2f * l0;
                float mn = fmaxf(m, l0);
                float sc = __expf(m - mn);
                float wgt = __expf(l0 - mn);
                z = z * sc + wgt;
                acc = acc * sc + wgt * __half2float(H[(size_t)s * 64 + lane]);
                m = mn;
            }
            float val = acc / z + bias[lane];
            if (RELU) val = fmaxf(val, 0.f);
            if (NORM) {
                float ss = val * val;
                #pragma unroll
                for (int o = 32; o > 0; o >>= 1) ss += __shfl_xor(ss, o, 64);
                val = val / fmaxf(sqrtf(ss), 1e-12f);
            }
            if (OUTH) ((__half*)outv)[(size_t)n * 64 + lane] = __float2half(val);
            else      ((float*)outv)[(size_t)n * 64 + lane] = val;
        }
    }
}

// ---------------- launch ----------------

extern "C" void kernel_launch(void* const* d_in, const int* in_sizes, int n_in,
                              void* d_out, int out_size, void* d_ws, size_t ws_size,
                              hipStream_t stream) {
    const float* x   = (const float*)d_in[0];
    const int*   ei  = (const int*)d_in[1];
    const float* W1  = (const float*)d_in[2];
    const float* as1 = (const float*)d_in[3];
    const float* ad1 = (const float*)d_in[4];
    const float* b1  = (const float*)d_in[5];
    const float* W2  = (const float*)d_in[6];
    const float* as2 = (const float*)d_in[7];
    const float* ad2 = (const float*)d_in[8];
    const float* b2  = (const float*)d_in[9];
    const int* src = ei;
    const int* dst = ei + NEDGES;

    char* ws = (char*)d_ws;
    size_t off = 0;
    auto alloc = [&](size_t bytes) -> void* {
        void* p = ws + off;
        off = (off + bytes + 255) & ~(size_t)255;
        return p;
    };
    __half* H    = (__half*)alloc((size_t)NNODES * 64 * 2);
    __half* OUT1 = (__half*)alloc((size_t)NNODES * 64 * 2);
    float* AS    = (float*)alloc((size_t)NNODES * 4);
    float* AD    = (float*)alloc((size_t)NNODES * 4);
    int*   offs  = (int*)alloc((size_t)(NNODES + 1) * 4);
    int*   ep    = (int*)alloc((size_t)NEDGES * 4);
    int*   esrc  = (int*)alloc((size_t)NEDGES * 4);
    int*   bcnt  = (int*)alloc((size_t)SCANL * 4);
    int*   boffs = (int*)alloc((size_t)SCANL * 4);
    int*   part1 = (int*)alloc((size_t)SCANB * 4);
    __half* Wt1  = (__half*)alloc((size_t)64 * 128 * 2);
    __half* Wt2  = (__half*)alloc((size_t)64 * 64 * 2);

    // CSR build + W prep (fused roles) — no global atomics
    k_bcount<<<NBLK1 + 2, 256, 0, stream>>>(dst, bcnt, W1, W2, Wt1, Wt2);
    k_scan_block<<<SCANB, 1024, 0, stream>>>(bcnt, boffs, part1, SCANL);
    // fused: MFMA gemm1 (blocks [0,782)) concurrent with bscatter
    k_gemm1_bscatter<<<NGEMM1 + NBLK1, 256, 0, stream>>>(
        x, Wt1, as1, ad1, H, AS, AD, src, dst, boffs, part1, ep);
    k_fine<<<NBUCK, 512, 0, stream>>>(ep, boffs, part1, offs, esrc);

    int aggBlocks = (NNODES / 2 + 3) / 4;  // 2 nodes/wave, 4 waves/block
    // Layer 1 aggregation
    k_agg<1, 0, 1><<<aggBlocks, 256, 0, stream>>>(esrc, offs, H, AS, AD, b1, OUT1, NNODES);

    // Layer 2
    k_gemm_att<64, 1><<<(NNODES + 63) / 64, 256, 0, stream>>>(OUT1, Wt2, as2, ad2, H, AS, AD, NNODES);
    k_agg<0, 1, 0><<<aggBlocks, 256, 0, stream>>>(esrc, offs, H, AS, AD, b2, d_out, NNODES);
}